// Round 1
// baseline (1786.887 us; speedup 1.0000x reference)
//
#include <hip/hip_runtime.h>
#include <hip/hip_bf16.h>

#define Lc 4
#define Nc 50000
#define Ec 800000
#define Dc 128
#define Hc 64
#define Bc 16384
#define EDc 256
#define Kc 7

#ifndef __HIP_DEVICE_COMPILE__
#endif

__device__ __forceinline__ void atomAddF(float* p, float v) {
#if defined(__gfx950__) || defined(__HIP_DEVICE_COMPILE__)
    unsafeAtomicAdd(p, v);
#else
    atomicAdd(p, v);
#endif
}

// ---------------- per-layer kernels ----------------

__global__ void k_deg(const int* __restrict__ dst, float* __restrict__ deg) {
    int e = blockIdx.x * 256 + threadIdx.x;
    if (e < Ec) atomAddF(&deg[dst[e]], 1.0f);
}

__global__ void k_dis(float* __restrict__ deg) {
    int n = blockIdx.x * 256 + threadIdx.x;
    if (n < Nc) deg[n] = rsqrtf(fmaxf(deg[n] + 1.0f, 1e-12f)); // +1 self loop
}

__global__ void k_s(const int* __restrict__ src, const int* __restrict__ dst,
                    const float* __restrict__ dis, const float* __restrict__ x,
                    float* __restrict__ s) {
    int e = blockIdx.x * 256 + threadIdx.x;
    if (e < Ec) {
        int si = src[e], di = dst[e];
        atomAddF(&s[di], dis[si] * dis[di] * x[si]);
    }
}

__global__ void k_stats(float* __restrict__ s, const float* __restrict__ dis,
                        const float* __restrict__ x, double* __restrict__ stats) {
    int n = blockIdx.x * 256 + threadIdx.x;
    double v = 0.0, v2 = 0.0;
    if (n < Nc) {
        float d = dis[n];
        float sf = s[n] + d * d * x[n];   // add self-loop contribution
        s[n] = sf;
        v = (double)sf;
        v2 = (double)sf * (double)sf;
    }
    for (int m = 32; m; m >>= 1) { v += __shfl_xor(v, m); v2 += __shfl_xor(v2, m); }
    __shared__ double red0[4], red1[4];
    int wid = threadIdx.x >> 6, lane = threadIdx.x & 63;
    if (lane == 0) { red0[wid] = v; red1[wid] = v2; }
    __syncthreads();
    if (threadIdx.x == 0) {
        double a = red0[0] + red0[1] + red0[2] + red0[3];
        double b = red1[0] + red1[1] + red1[2] + red1[3];
        atomicAdd(&stats[0], a);
        atomicAdd(&stats[1], b);
    }
}

__global__ void k_cvec(const double* __restrict__ stats, const float* __restrict__ W1,
                       const float* __restrict__ gamma, float* __restrict__ cbuf) {
    int h = threadIdx.x; // 64
    double mean = stats[0] / (double)Nc;
    double var = stats[1] / (double)Nc - mean * mean;
    float w = W1[h];
    cbuf[h] = gamma[h] * w * rsqrtf((float)var * w * w + 1e-5f);
    if (h == 0) cbuf[64] = (float)mean;
}

__global__ void k_h(const float* __restrict__ s, const float* __restrict__ dis,
                    const float* __restrict__ cbuf, const float* __restrict__ beta,
                    float* __restrict__ h, float* __restrict__ acc) {
    int i = blockIdx.x * 256 + threadIdx.x; // N*64 threads
    int n = i >> 6, hh = i & 63;
    float t = s[n] - cbuf[64];
    float hv = fmaxf(cbuf[hh] * t + beta[hh], 0.0f);
    h[i] = hv;
    float dn = dis[n];
    acc[i] = dn * dn * hv;   // self-loop contribution initializes acc
}

// one wave per edge; lane = feature
__global__ void k_scat2(const int* __restrict__ src, const int* __restrict__ dst,
                        const float* __restrict__ dis, const float* __restrict__ h,
                        float* __restrict__ acc) {
    int tid = blockIdx.x * 256 + threadIdx.x;
    int e = tid >> 6, lane = tid & 63;
    if (e < Ec) {
        int si = src[e], di = dst[e];
        float nm = dis[si] * dis[di];
        atomAddF(&acc[di * 64 + lane], nm * h[si * 64 + lane]);
    }
}

__global__ void k_gemm2(const float* __restrict__ acc, const float* __restrict__ W2,
                        const float* __restrict__ b2, float* __restrict__ embed) {
    int i = blockIdx.x * 256 + threadIdx.x; // N*128 threads
    int n = i >> 7, d = i & 127;
    float v = b2[d];
    const float* ar = acc + n * 64;
#pragma unroll 8
    for (int hh = 0; hh < 64; hh++) v += ar[hh] * W2[hh * 128 + d];
    embed[i] = v;
}

__global__ void k_gather(const int* __restrict__ now, const int* __restrict__ ln,
                         const int* __restrict__ rn, const float* __restrict__ embed,
                         float* __restrict__ ls, int l) {
    int b = blockIdx.x, t = threadIdx.x; // 128 threads
    if (now[b] != l) return;
    ls[b * 256 + t]       = embed[ln[b] * 128 + t];
    ls[b * 256 + 128 + t] = embed[rn[b] * 128 + t];
}

// ---------------- tail kernels ----------------

__global__ void k_wT(const float* __restrict__ w, float* __restrict__ wT) {
    int i = blockIdx.x * 256 + threadIdx.x; // 256*256*7
    int co = i / (EDc * Kc);
    int r = i % (EDc * Kc);
    int ci = r / Kc, k = r % Kc;
    wT[(k * EDc + ci) * EDc + co] = w[i];
}

#define NB 32
__global__ __launch_bounds__(256) void k_conv(const float* __restrict__ ls,
                                              const float* __restrict__ wT,
                                              const float* __restrict__ cb,
                                              float* __restrict__ sh) {
    __shared__ float lss[NB + 6][EDc];
    int b0 = blockIdx.x * NB;
    int co = threadIdx.x;
    for (int r = 0; r < NB + 6; r++) {
        int row = b0 - 3 + r;
        lss[r][co] = (row >= 0 && row < Bc) ? ls[row * EDc + co] : 0.0f;
    }
    __syncthreads();
    float acc[NB];
#pragma unroll
    for (int j = 0; j < NB; j++) acc[j] = 0.0f;
    float bias = cb[co];
    for (int ci = 0; ci < EDc; ci++) {
        float wv[Kc];
#pragma unroll
        for (int k = 0; k < Kc; k++) wv[k] = wT[(k * EDc + ci) * EDc + co];
        float lv[NB + 6];
#pragma unroll
        for (int r = 0; r < NB + 6; r++) lv[r] = lss[r][ci];
#pragma unroll
        for (int j = 0; j < NB; j++) {
#pragma unroll
            for (int k = 0; k < Kc; k++) acc[j] += wv[k] * lv[j + k];
        }
    }
    for (int j = 0; j < NB; j++)
        sh[(b0 + j) * EDc + co] = fmaxf(acc[j] + bias, 0.0f);
}

__global__ void k_final(const float* __restrict__ ls, const float* __restrict__ sh,
                        const float* __restrict__ lc_w, const float* __restrict__ lc_b,
                        const float* __restrict__ link_w, const float* __restrict__ link_b,
                        float* __restrict__ out) {
    int b = blockIdx.x, lane = threadIdx.x; // 64 threads
    float lsv[4], shv[4];
    float dot = 0.f, nrm = 0.f;
#pragma unroll
    for (int i = 0; i < 4; i++) {
        int ci = lane + i * 64;
        lsv[i] = ls[b * 256 + ci];
        shv[i] = sh[b * 256 + ci];
        dot += lsv[i] * shv[i];
        nrm += shv[i] * shv[i];
    }
    for (int m = 32; m; m >>= 1) { dot += __shfl_xor(dot, m); nrm += __shfl_xor(nrm, m); }
    float coef = dot / (nrm + 1e-12f);
    float p0 = 0.f, p1 = 0.f, d0 = 0.f, d1 = 0.f, d2 = 0.f, d3 = 0.f;
#pragma unroll
    for (int i = 0; i < 4; i++) {
        int ci = lane + i * 64;
        float e = lsv[i] - coef * shv[i] + shv[i];
        p0 += e * link_w[ci * 2];
        p1 += e * link_w[ci * 2 + 1];
        d0 += shv[i] * lc_w[ci * 4];
        d1 += shv[i] * lc_w[ci * 4 + 1];
        d2 += shv[i] * lc_w[ci * 4 + 2];
        d3 += shv[i] * lc_w[ci * 4 + 3];
    }
    for (int m = 32; m; m >>= 1) {
        p0 += __shfl_xor(p0, m); p1 += __shfl_xor(p1, m);
        d0 += __shfl_xor(d0, m); d1 += __shfl_xor(d1, m);
        d2 += __shfl_xor(d2, m); d3 += __shfl_xor(d3, m);
    }
    if (lane == 0) {
        out[b * 2]     = p0 + link_b[0];
        out[b * 2 + 1] = p1 + link_b[1];
        float* dd = out + 2 * Bc;
        dd[b * 4]     = d0 + lc_b[0];
        dd[b * 4 + 1] = d1 + lc_b[1];
        dd[b * 4 + 2] = d2 + lc_b[2];
        dd[b * 4 + 3] = d3 + lc_b[3];
    }
}

// ---------------- launch ----------------

extern "C" void kernel_launch(void* const* d_in, const int* in_sizes, int n_in,
                              void* d_out, int out_size, void* d_ws, size_t ws_size,
                              hipStream_t stream) {
    const float* x_nodes    = (const float*)d_in[0];
    const int*   edge_index = (const int*)d_in[1];
    const float* W1   = (const float*)d_in[2];
    // d_in[3] = b1 (cancels in BN)
    const float* gamma = (const float*)d_in[4];
    const float* beta  = (const float*)d_in[5];
    const float* W2   = (const float*)d_in[6];
    const float* b2   = (const float*)d_in[7];
    const float* conv_w = (const float*)d_in[8];
    const float* conv_b = (const float*)d_in[9];
    const float* lc_w   = (const float*)d_in[10];
    const float* lc_b   = (const float*)d_in[11];
    const float* link_w = (const float*)d_in[12];
    const float* link_b = (const float*)d_in[13];
    const int* now = (const int*)d_in[14];
    const int* ln  = (const int*)d_in[15];
    const int* rn  = (const int*)d_in[16];
    float* out = (float*)d_out;

    // workspace carving (all offsets 256B aligned)
    char* base = (char*)d_ws;
    size_t off = 0;
    auto carve = [&](size_t bytes) {
        void* p = base + off;
        off = (off + bytes + 255) & ~(size_t)255;
        return p;
    };
    float*  deg   = (float*)carve(Nc * 4);          // becomes dis in-place
    float*  s     = (float*)carve(Nc * 4);
    double* stats = (double*)carve(4 * 8);
    float*  cbuf  = (float*)carve(72 * 4);
    float*  h     = (float*)carve((size_t)Nc * 64 * 4);
    float*  acc   = (float*)carve((size_t)Nc * 64 * 4);
    float*  embed = (float*)carve((size_t)Nc * 128 * 4);
    float*  lsb   = (float*)carve((size_t)Bc * 256 * 4);
    float*  shb   = (float*)carve((size_t)Bc * 256 * 4);
    float*  wT    = (float*)carve((size_t)EDc * EDc * Kc * 4);
    (void)ws_size;

    // weight transpose once per call (independent of layer loop)
    k_wT<<<1792, 256, 0, stream>>>(conv_w, wT);

    for (int l = 0; l < Lc; l++) {
        const int* ei  = edge_index + (size_t)l * 2 * Ec;
        const int* src = ei;
        const int* dst = ei + Ec;
        const float* xl = x_nodes + (size_t)l * Nc;

        // zero deg, s, stats in one memset (they are contiguous in ws)
        hipMemsetAsync(deg, 0, (char*)(stats + 4) - (char*)deg, stream);

        k_deg<<<(Ec + 255) / 256, 256, 0, stream>>>(dst, deg);
        k_dis<<<(Nc + 255) / 256, 256, 0, stream>>>(deg);
        k_s<<<(Ec + 255) / 256, 256, 0, stream>>>(src, dst, deg, xl, s);
        k_stats<<<(Nc + 255) / 256, 256, 0, stream>>>(s, deg, xl, stats);
        k_cvec<<<1, 64, 0, stream>>>(stats, W1 + l * 64, gamma + l * 64, cbuf);
        k_h<<<(Nc * 64) / 256, 256, 0, stream>>>(s, deg, cbuf, beta + l * 64, h, acc);
        k_scat2<<<(Ec * 64) / 256, 256, 0, stream>>>(src, dst, deg, h, acc);
        k_gemm2<<<(Nc * 128) / 256, 256, 0, stream>>>(acc, W2 + l * 64 * 128, b2 + l * 128, embed);
        k_gather<<<Bc, 128, 0, stream>>>(now, ln, rn, embed, lsb, l);
    }

    k_conv<<<Bc / NB, 256, 0, stream>>>(lsb, wT, conv_b, shb);
    k_final<<<Bc, 64, 0, stream>>>(lsb, shb, lc_w, lc_b, link_w, link_b, out);
}

// Round 2
// 778.854 us; speedup vs baseline: 2.2943x; 2.2943x over previous
//
#include <hip/hip_runtime.h>
#include <hip/hip_bf16.h>

#define Lc 4
#define Nc 50000
#define Ec 800000
#define Bc 16384
#define EDc 256
#define Kc 7

// ---------------- per-layer: CSR build ----------------

__global__ void k_count(const int* __restrict__ dst, int* __restrict__ cnt) {
    int e = blockIdx.x * 256 + threadIdx.x;
    if (e < Ec) atomicAdd(&cnt[dst[e]], 1);
}

__global__ void k_scan1(const int* __restrict__ cnt, int* __restrict__ tmp,
                        int* __restrict__ bsum) {
    int i = blockIdx.x * 256 + threadIdx.x;
    int lane = threadIdx.x & 63, wid = threadIdx.x >> 6;
    int v = (i < Nc) ? cnt[i] : 0;
    int x = v;
#pragma unroll
    for (int off = 1; off < 64; off <<= 1) {
        int y = __shfl_up(x, off);
        if (lane >= off) x += y;
    }
    __shared__ int ws[4];
    if (lane == 63) ws[wid] = x;
    __syncthreads();
    for (int w = 0; w < wid; w++) x += ws[w];
    if (i < Nc) tmp[i] = x;                 // inclusive within block
    if (threadIdx.x == 255) bsum[blockIdx.x] = x;
}

__global__ void k_scan2(int* __restrict__ bsum, int nb) {
    int i = threadIdx.x;
    int lane = threadIdx.x & 63, wid = threadIdx.x >> 6;
    int v = (i < nb) ? bsum[i] : 0;
    int x = v;
#pragma unroll
    for (int off = 1; off < 64; off <<= 1) {
        int y = __shfl_up(x, off);
        if (lane >= off) x += y;
    }
    __shared__ int ws[4];
    if (lane == 63) ws[wid] = x;
    __syncthreads();
    for (int w = 0; w < wid; w++) x += ws[w];
    __syncthreads();
    if (i < nb) bsum[i] = x - v;            // exclusive block offsets
}

__global__ void k_scan3(const int* __restrict__ cnt, const int* __restrict__ tmp,
                        const int* __restrict__ bsum, int* __restrict__ row_start,
                        int* __restrict__ cursor, float* __restrict__ dis) {
    int i = blockIdx.x * 256 + threadIdx.x;
    if (i < Nc) {
        int rs = tmp[i] - cnt[i] + bsum[i >> 8];
        row_start[i] = rs;
        cursor[i] = rs;
        dis[i] = rsqrtf((float)cnt[i] + 1.0f);   // +1 = self loop
    }
}

__global__ void k_fill(const int* __restrict__ src, const int* __restrict__ dst,
                       int* __restrict__ cursor, int* __restrict__ csr) {
    int e = blockIdx.x * 256 + threadIdx.x;
    if (e < Ec) {
        int pos = atomicAdd(&cursor[dst[e]], 1);
        csr[pos] = src[e];
    }
}

// ---------------- per-layer: scalar aggregation + BN stats ----------------

__global__ void k_s_stats(const int* __restrict__ row_start, const int* __restrict__ cnt,
                          const int* __restrict__ csr, const float* __restrict__ dis,
                          const float* __restrict__ x, float* __restrict__ s,
                          double* __restrict__ stats) {
    int n = blockIdx.x * 256 + threadIdx.x;
    double v = 0.0, v2 = 0.0;
    if (n < Nc) {
        int st = row_start[n], en = st + cnt[n];
        float t = 0.f;
        for (int e = st; e < en; e++) {
            int sv = csr[e];
            t += dis[sv] * x[sv];
        }
        float dn = dis[n];
        float sf = dn * t + dn * dn * x[n];   // neighbors + self loop
        s[n] = sf;
        v = (double)sf;
        v2 = (double)sf * (double)sf;
    }
    for (int m = 32; m; m >>= 1) { v += __shfl_xor(v, m); v2 += __shfl_xor(v2, m); }
    __shared__ double r0[4], r1[4];
    int wid = threadIdx.x >> 6, lane = threadIdx.x & 63;
    if (lane == 0) { r0[wid] = v; r1[wid] = v2; }
    __syncthreads();
    if (threadIdx.x == 0) {
        atomicAdd(&stats[0], r0[0] + r0[1] + r0[2] + r0[3]);
        atomicAdd(&stats[1], r1[0] + r1[1] + r1[2] + r1[3]);
    }
}

__global__ void k_cvec(const double* __restrict__ stats, const float* __restrict__ W1,
                       const float* __restrict__ gamma, float* __restrict__ cbuf) {
    int h = threadIdx.x; // 64
    double mean = stats[0] / (double)Nc;
    double var = stats[1] / (double)Nc - mean * mean;
    float w = W1[h];
    cbuf[h] = gamma[h] * w * rsqrtf((float)var * w * w + 1e-5f);
    if (h == 0) cbuf[64] = (float)mean;
}

// ---------------- per-layer: per-sample node embedding ----------------
// For each sample with now[b]==l: aggregate in-edges of left/right node
// (reconstructing h from scalar s on the fly), then 64x128 GEMM with W2.

__global__ __launch_bounds__(128) void k_embed(const int* __restrict__ now,
        const int* __restrict__ lnn, const int* __restrict__ rnn,
        const int* __restrict__ row_start, const int* __restrict__ cnt,
        const int* __restrict__ csr, const float* __restrict__ dis,
        const float* __restrict__ s, const float* __restrict__ cbuf,
        const float* __restrict__ beta, const float* __restrict__ W2,
        const float* __restrict__ b2, float* __restrict__ lsb, int l) {
    int b = blockIdx.x;
    if (now[b] != l) return;
    int side = threadIdx.x >> 6, lane = threadIdx.x & 63;
    int n = side ? rnn[b] : lnn[b];
    float c = cbuf[lane], mu = cbuf[64], bt = beta[lane];
    int st = row_start[n], deg = cnt[n];
    float a = 0.f;
    for (int base = 0; base < deg; base += 64) {
        int e = base + lane;
        int sv = (e < deg) ? csr[st + e] : 0;
        float nv = (e < deg) ? dis[sv] : 0.f;
        float fv = (e < deg) ? s[sv] : 0.f;
        int m = min(64, deg - base);
        for (int j = 0; j < m; j++) {
            float nj = __shfl(nv, j);
            float fj = __shfl(fv, j);
            float hv = fmaxf(c * (fj - mu) + bt, 0.f);   // h[src][lane]
            a += nj * hv;
        }
    }
    float dn = dis[n];
    float hself = fmaxf(c * (s[n] - mu) + bt, 0.f);
    a = dn * a + dn * dn * hself;      // acc_h[lane] for node n
    // embed[d] = sum_h acc_h * W2[h][d] + b2[d], d = lane, lane+64
    float o0 = b2[lane], o1 = b2[lane + 64];
    for (int hh = 0; hh < 64; hh++) {
        float ah = __shfl(a, hh);
        o0 += ah * W2[hh * 128 + lane];
        o1 += ah * W2[hh * 128 + lane + 64];
    }
    float* outp = lsb + (size_t)b * 256 + side * 128;
    outp[lane] = o0;
    outp[lane + 64] = o1;
}

// ---------------- tail kernels ----------------

__global__ void k_wT(const float* __restrict__ w, float* __restrict__ wT) {
    int i = blockIdx.x * 256 + threadIdx.x; // 256*256*7
    int co = i / (EDc * Kc);
    int r = i % (EDc * Kc);
    int ci = r / Kc, k = r % Kc;
    wT[(k * EDc + ci) * EDc + co] = w[i];
}

#define NB 32
#define NBH 16
__global__ __launch_bounds__(512) void k_conv(const float* __restrict__ ls,
                                              const float* __restrict__ wT,
                                              const float* __restrict__ cb,
                                              float* __restrict__ sh) {
    __shared__ float lss[NB + 6][EDc];
    int b0 = blockIdx.x * NB;
    int co = threadIdx.x & 255;
    int g = threadIdx.x >> 8;            // 0 or 1: row-half
    for (int r = g; r < NB + 6; r += 2) {
        int row = b0 - 3 + r;
        lss[r][co] = (row >= 0 && row < Bc) ? ls[row * EDc + co] : 0.0f;
    }
    __syncthreads();
    float acc[NBH];
#pragma unroll
    for (int j = 0; j < NBH; j++) acc[j] = 0.0f;
    int r0 = g * NBH;
    for (int ci = 0; ci < EDc; ci++) {
        float wv[Kc];
#pragma unroll
        for (int k = 0; k < Kc; k++) wv[k] = wT[(k * EDc + ci) * EDc + co];
        float lv[NBH + 6];
#pragma unroll
        for (int r = 0; r < NBH + 6; r++) lv[r] = lss[r0 + r][ci];
#pragma unroll
        for (int j = 0; j < NBH; j++) {
#pragma unroll
            for (int k = 0; k < Kc; k++) acc[j] += wv[k] * lv[j + k];
        }
    }
    float bias = cb[co];
    for (int j = 0; j < NBH; j++)
        sh[(b0 + r0 + j) * EDc + co] = fmaxf(acc[j] + bias, 0.0f);
}

__global__ void k_final(const float* __restrict__ ls, const float* __restrict__ sh,
                        const float* __restrict__ lc_w, const float* __restrict__ lc_b,
                        const float* __restrict__ link_w, const float* __restrict__ link_b,
                        float* __restrict__ out) {
    int b = blockIdx.x, lane = threadIdx.x; // 64 threads
    float lsv[4], shv[4];
    float dot = 0.f, nrm = 0.f;
#pragma unroll
    for (int i = 0; i < 4; i++) {
        int ci = lane + i * 64;
        lsv[i] = ls[b * 256 + ci];
        shv[i] = sh[b * 256 + ci];
        dot += lsv[i] * shv[i];
        nrm += shv[i] * shv[i];
    }
    for (int m = 32; m; m >>= 1) { dot += __shfl_xor(dot, m); nrm += __shfl_xor(nrm, m); }
    float coef = dot / (nrm + 1e-12f);
    float p0 = 0.f, p1 = 0.f, d0 = 0.f, d1 = 0.f, d2 = 0.f, d3 = 0.f;
#pragma unroll
    for (int i = 0; i < 4; i++) {
        int ci = lane + i * 64;
        float e = lsv[i] - coef * shv[i] + shv[i];
        p0 += e * link_w[ci * 2];
        p1 += e * link_w[ci * 2 + 1];
        d0 += shv[i] * lc_w[ci * 4];
        d1 += shv[i] * lc_w[ci * 4 + 1];
        d2 += shv[i] * lc_w[ci * 4 + 2];
        d3 += shv[i] * lc_w[ci * 4 + 3];
    }
    for (int m = 32; m; m >>= 1) {
        p0 += __shfl_xor(p0, m); p1 += __shfl_xor(p1, m);
        d0 += __shfl_xor(d0, m); d1 += __shfl_xor(d1, m);
        d2 += __shfl_xor(d2, m); d3 += __shfl_xor(d3, m);
    }
    if (lane == 0) {
        out[b * 2]     = p0 + link_b[0];
        out[b * 2 + 1] = p1 + link_b[1];
        float* dd = out + 2 * Bc;
        dd[b * 4]     = d0 + lc_b[0];
        dd[b * 4 + 1] = d1 + lc_b[1];
        dd[b * 4 + 2] = d2 + lc_b[2];
        dd[b * 4 + 3] = d3 + lc_b[3];
    }
}

// ---------------- launch ----------------

extern "C" void kernel_launch(void* const* d_in, const int* in_sizes, int n_in,
                              void* d_out, int out_size, void* d_ws, size_t ws_size,
                              hipStream_t stream) {
    const float* x_nodes    = (const float*)d_in[0];
    const int*   edge_index = (const int*)d_in[1];
    const float* W1   = (const float*)d_in[2];
    // d_in[3] = b1 (cancels in BN)
    const float* gamma = (const float*)d_in[4];
    const float* beta  = (const float*)d_in[5];
    const float* W2   = (const float*)d_in[6];
    const float* b2   = (const float*)d_in[7];
    const float* conv_w = (const float*)d_in[8];
    const float* conv_b = (const float*)d_in[9];
    const float* lc_w   = (const float*)d_in[10];
    const float* lc_b   = (const float*)d_in[11];
    const float* link_w = (const float*)d_in[12];
    const float* link_b = (const float*)d_in[13];
    const int* now = (const int*)d_in[14];
    const int* ln  = (const int*)d_in[15];
    const int* rn  = (const int*)d_in[16];
    float* out = (float*)d_out;

    char* base = (char*)d_ws;
    size_t off = 0;
    auto carve = [&](size_t bytes) {
        void* p = base + off;
        off = (off + bytes + 255) & ~(size_t)255;
        return p;
    };
    int*    cnt    = (int*)carve((size_t)Nc * 4);
    double* stats  = (double*)carve(4 * 8);           // adjacent to cnt: one memset
    int*    tmp    = (int*)carve((size_t)Nc * 4);
    int*    bsum   = (int*)carve(256 * 4);
    int*    rstart = (int*)carve((size_t)Nc * 4);
    int*    cursor = (int*)carve((size_t)Nc * 4);
    int*    csr    = (int*)carve((size_t)Ec * 4);
    float*  dis    = (float*)carve((size_t)Nc * 4);
    float*  s      = (float*)carve((size_t)Nc * 4);
    float*  cbuf   = (float*)carve(72 * 4);
    float*  lsb    = (float*)carve((size_t)Bc * 256 * 4);
    float*  shb    = (float*)carve((size_t)Bc * 256 * 4);
    float*  wT     = (float*)carve((size_t)EDc * EDc * Kc * 4);
    (void)ws_size;

    const int EB = (Ec + 255) / 256;   // 3125
    const int NBK = (Nc + 255) / 256;  // 196

    k_wT<<<1792, 256, 0, stream>>>(conv_w, wT);

    for (int l = 0; l < Lc; l++) {
        const int* ei  = edge_index + (size_t)l * 2 * Ec;
        const int* src = ei;
        const int* dst = ei + Ec;
        const float* xl = x_nodes + (size_t)l * Nc;

        hipMemsetAsync(cnt, 0, (char*)(stats + 4) - (char*)cnt, stream);

        k_count<<<EB, 256, 0, stream>>>(dst, cnt);
        k_scan1<<<NBK, 256, 0, stream>>>(cnt, tmp, bsum);
        k_scan2<<<1, 256, 0, stream>>>(bsum, NBK);
        k_scan3<<<NBK, 256, 0, stream>>>(cnt, tmp, bsum, rstart, cursor, dis);
        k_fill<<<EB, 256, 0, stream>>>(src, dst, cursor, csr);
        k_s_stats<<<NBK, 256, 0, stream>>>(rstart, cnt, csr, dis, xl, s, stats);
        k_cvec<<<1, 64, 0, stream>>>(stats, W1 + l * 64, gamma + l * 64, cbuf);
        k_embed<<<Bc, 128, 0, stream>>>(now, ln, rn, rstart, cnt, csr, dis, s,
                                        cbuf, beta + l * 64, W2 + (size_t)l * 64 * 128,
                                        b2 + (size_t)l * 128, lsb, l);
    }

    k_conv<<<Bc / NB, 512, 0, stream>>>(lsb, wT, conv_b, shb);
    k_final<<<Bc, 64, 0, stream>>>(lsb, shb, lc_w, lc_b, link_w, link_b, out);
}

// Round 3
// 716.153 us; speedup vs baseline: 2.4951x; 1.0876x over previous
//
#include <hip/hip_runtime.h>
#include <hip/hip_bf16.h>

#define Lc 4
#define Nc 50000
#define Ec 800000
#define Bc 16384
#define EDc 256
#define Kc 7
#define Mtot (Lc * Nc)      // 200000 nodes total
#define NBK 196             // blocks per layer for node-parallel kernels
#define SB 782              // scan blocks over Mtot

// ---------------- CSR build, all 4 layers at once ----------------

__global__ void k_count4(const int* __restrict__ ei, int* __restrict__ cnt) {
    int l = blockIdx.y;
    int idx = blockIdx.x * 256 + threadIdx.x;
    if (idx < Ec) {
        int dst = ei[(size_t)l * 2 * Ec + Ec + idx];
        atomicAdd(&cnt[l * Nc + dst], 1);
    }
}

__global__ void k_scan1(const int* __restrict__ cnt, int* __restrict__ tmp,
                        int* __restrict__ bsum) {
    int i = blockIdx.x * 256 + threadIdx.x;
    int lane = threadIdx.x & 63, wid = threadIdx.x >> 6;
    int v = (i < Mtot) ? cnt[i] : 0;
    int x = v;
#pragma unroll
    for (int off = 1; off < 64; off <<= 1) {
        int y = __shfl_up(x, off);
        if (lane >= off) x += y;
    }
    __shared__ int ws[4];
    if (lane == 63) ws[wid] = x;
    __syncthreads();
    for (int w = 0; w < wid; w++) x += ws[w];
    if (i < Mtot) tmp[i] = x;                 // inclusive within block
    if (threadIdx.x == 255) bsum[blockIdx.x] = x;
}

__global__ __launch_bounds__(1024) void k_scan2(int* __restrict__ bsum, int nb) {
    int i = threadIdx.x;
    int lane = i & 63, wid = i >> 6;
    int v = (i < nb) ? bsum[i] : 0;
    int x = v;
#pragma unroll
    for (int off = 1; off < 64; off <<= 1) {
        int y = __shfl_up(x, off);
        if (lane >= off) x += y;
    }
    __shared__ int ws[16];
    if (lane == 63) ws[wid] = x;
    __syncthreads();
    for (int w = 0; w < wid; w++) x += ws[w];
    if (i < nb) bsum[i] = x - v;              // exclusive block offsets
}

__global__ void k_scan3(const int* __restrict__ cnt, const int* __restrict__ tmp,
                        const int* __restrict__ bsum, int* __restrict__ row_start,
                        int* __restrict__ cursor, float* __restrict__ dis) {
    int i = blockIdx.x * 256 + threadIdx.x;
    if (i < Mtot) {
        int rs = tmp[i] - cnt[i] + bsum[i >> 8];
        row_start[i] = rs;
        cursor[i] = rs;
        dis[i] = rsqrtf((float)cnt[i] + 1.0f);   // +1 = self loop
    }
}

__global__ void k_fill4(const int* __restrict__ ei, int* __restrict__ cursor,
                        int* __restrict__ csr) {
    int l = blockIdx.y;
    int idx = blockIdx.x * 256 + threadIdx.x;
    if (idx < Ec) {
        int src = ei[(size_t)l * 2 * Ec + idx];
        int dst = ei[(size_t)l * 2 * Ec + Ec + idx];
        int pos = atomicAdd(&cursor[l * Nc + dst], 1);
        csr[pos] = src;    // global position: layer l occupies [l*Ec,(l+1)*Ec)
    }
}

// ---------------- scalar aggregation + BN stats (per layer segment) --------

__global__ void k_s_stats4(const int* __restrict__ row_start, const int* __restrict__ cnt,
                           const int* __restrict__ csr, const float* __restrict__ dis,
                           const float* __restrict__ x_nodes, float* __restrict__ s,
                           double* __restrict__ stats) {
    int l = blockIdx.x / NBK;
    int n = (blockIdx.x % NBK) * 256 + threadIdx.x;
    double v = 0.0, v2 = 0.0;
    if (n < Nc) {
        int n4 = l * Nc + n;
        const float* x = x_nodes + (size_t)l * Nc;
        const float* dl = dis + (size_t)l * Nc;
        int st = row_start[n4], en = st + cnt[n4];
        float t = 0.f;
        for (int e = st; e < en; e++) {
            int sv = csr[e];
            t += dl[sv] * x[sv];
        }
        float dn = dl[n];
        float sf = dn * t + dn * dn * x[n];   // neighbors + self loop
        s[n4] = sf;
        v = (double)sf;
        v2 = (double)sf * (double)sf;
    }
    for (int m = 32; m; m >>= 1) { v += __shfl_xor(v, m); v2 += __shfl_xor(v2, m); }
    __shared__ double r0[4], r1[4];
    int wid = threadIdx.x >> 6, lane = threadIdx.x & 63;
    if (lane == 0) { r0[wid] = v; r1[wid] = v2; }
    __syncthreads();
    if (threadIdx.x == 0) {
        atomicAdd(&stats[l * 2 + 0], r0[0] + r0[1] + r0[2] + r0[3]);
        atomicAdd(&stats[l * 2 + 1], r1[0] + r1[1] + r1[2] + r1[3]);
    }
}

__global__ void k_cvec4(const double* __restrict__ stats, const float* __restrict__ W1,
                        const float* __restrict__ gamma, float* __restrict__ cbuf) {
    int l = threadIdx.x >> 6, h = threadIdx.x & 63;  // 256 threads
    double mean = stats[l * 2] / (double)Nc;
    double var = stats[l * 2 + 1] / (double)Nc - mean * mean;
    float w = W1[l * 64 + h];
    cbuf[l * 72 + h] = gamma[l * 64 + h] * w * rsqrtf((float)var * w * w + 1e-5f);
    if (h == 0) cbuf[l * 72 + 64] = (float)mean;
}

// ---------------- per-sample node embedding (all samples, own layer) -------

__global__ __launch_bounds__(128) void k_embed4(const int* __restrict__ now,
        const int* __restrict__ lnn, const int* __restrict__ rnn,
        const int* __restrict__ row_start, const int* __restrict__ cnt,
        const int* __restrict__ csr, const float* __restrict__ dis,
        const float* __restrict__ s, const float* __restrict__ cbuf,
        const float* __restrict__ beta, const float* __restrict__ W2,
        const float* __restrict__ b2, float* __restrict__ lsb) {
    int b = blockIdx.x;
    int l = now[b];
    int side = threadIdx.x >> 6, lane = threadIdx.x & 63;
    int n = side ? rnn[b] : lnn[b];
    int n4 = l * Nc + n;
    float c = cbuf[l * 72 + lane], mu = cbuf[l * 72 + 64], bt = beta[l * 64 + lane];
    const float* dl = dis + (size_t)l * Nc;
    const float* sl = s + (size_t)l * Nc;
    int st = row_start[n4], deg = cnt[n4];
    float a = 0.f;
    for (int base = 0; base < deg; base += 64) {
        int e = base + lane;
        int sv = (e < deg) ? csr[st + e] : 0;
        float nv = (e < deg) ? dl[sv] : 0.f;
        float fv = (e < deg) ? sl[sv] : 0.f;
        int m = min(64, deg - base);
        for (int j = 0; j < m; j++) {
            float nj = __shfl(nv, j);
            float fj = __shfl(fv, j);
            float hv = fmaxf(c * (fj - mu) + bt, 0.f);   // h[src][lane]
            a += nj * hv;
        }
    }
    float dn = dl[n];
    float hself = fmaxf(c * (sl[n] - mu) + bt, 0.f);
    a = dn * a + dn * dn * hself;      // acc_h[lane] for node n
    const float* W2l = W2 + (size_t)l * 64 * 128;
    const float* b2l = b2 + (size_t)l * 128;
    float o0 = b2l[lane], o1 = b2l[lane + 64];
    for (int hh = 0; hh < 64; hh++) {
        float ah = __shfl(a, hh);
        o0 += ah * W2l[hh * 128 + lane];
        o1 += ah * W2l[hh * 128 + lane + 64];
    }
    float* outp = lsb + (size_t)b * 256 + side * 128;
    outp[lane] = o0;
    outp[lane + 64] = o1;
}

// ---------------- tail kernels ----------------

// conv_w [co][ci][k] -> wT [ci][k][co]
__global__ void k_wT(const float* __restrict__ w, float* __restrict__ wT) {
    int i = blockIdx.x * 256 + threadIdx.x; // 256*256*7 = 458752
    wT[(i % (EDc * Kc)) * EDc + i / (EDc * Kc)] = w[i];
}

#define NB 32
__global__ __launch_bounds__(256) void k_conv(const float* __restrict__ ls,
                                              const float* __restrict__ wT,
                                              const float* __restrict__ cb,
                                              float* __restrict__ sh) {
    __shared__ float lss[NB + 6][EDc];
    int b0 = blockIdx.x * NB;
    int co = threadIdx.x;
    for (int r = 0; r < NB + 6; r++) {
        int row = b0 - 3 + r;
        lss[r][co] = (row >= 0 && row < Bc) ? ls[row * EDc + co] : 0.0f;
    }
    __syncthreads();
    float acc[NB];
#pragma unroll
    for (int j = 0; j < NB; j++) acc[j] = 0.0f;
    for (int ci = 0; ci < EDc; ci += 4) {
        float wv[4][Kc];
        const float* wp = wT + (size_t)ci * Kc * EDc + co;
#pragma unroll
        for (int u = 0; u < 4; u++)
#pragma unroll
            for (int k = 0; k < Kc; k++)
                wv[u][k] = wp[(u * Kc + k) * EDc];
#pragma unroll
        for (int rr = 0; rr < NB + 6; rr++) {
            float4 lv = *(const float4*)&lss[rr][ci];
            float lvf[4] = {lv.x, lv.y, lv.z, lv.w};
#pragma unroll
            for (int u = 0; u < 4; u++)
#pragma unroll
                for (int k = 0; k < Kc; k++) {
                    int j = rr - k;
                    if (j >= 0 && j < NB) acc[j] += wv[u][k] * lvf[u];
                }
        }
    }
    float bias = cb[co];
#pragma unroll
    for (int j = 0; j < NB; j++)
        sh[(size_t)(b0 + j) * EDc + co] = fmaxf(acc[j] + bias, 0.0f);
}

__global__ void k_final(const float* __restrict__ ls, const float* __restrict__ sh,
                        const float* __restrict__ lc_w, const float* __restrict__ lc_b,
                        const float* __restrict__ link_w, const float* __restrict__ link_b,
                        float* __restrict__ out) {
    int b = blockIdx.x, lane = threadIdx.x; // 64 threads
    float lsv[4], shv[4];
    float dot = 0.f, nrm = 0.f;
#pragma unroll
    for (int i = 0; i < 4; i++) {
        int ci = lane + i * 64;
        lsv[i] = ls[b * 256 + ci];
        shv[i] = sh[b * 256 + ci];
        dot += lsv[i] * shv[i];
        nrm += shv[i] * shv[i];
    }
    for (int m = 32; m; m >>= 1) { dot += __shfl_xor(dot, m); nrm += __shfl_xor(nrm, m); }
    float coef = dot / (nrm + 1e-12f);
    float p0 = 0.f, p1 = 0.f, d0 = 0.f, d1 = 0.f, d2 = 0.f, d3 = 0.f;
#pragma unroll
    for (int i = 0; i < 4; i++) {
        int ci = lane + i * 64;
        float e = lsv[i] - coef * shv[i] + shv[i];
        p0 += e * link_w[ci * 2];
        p1 += e * link_w[ci * 2 + 1];
        d0 += shv[i] * lc_w[ci * 4];
        d1 += shv[i] * lc_w[ci * 4 + 1];
        d2 += shv[i] * lc_w[ci * 4 + 2];
        d3 += shv[i] * lc_w[ci * 4 + 3];
    }
    for (int m = 32; m; m >>= 1) {
        p0 += __shfl_xor(p0, m); p1 += __shfl_xor(p1, m);
        d0 += __shfl_xor(d0, m); d1 += __shfl_xor(d1, m);
        d2 += __shfl_xor(d2, m); d3 += __shfl_xor(d3, m);
    }
    if (lane == 0) {
        out[b * 2]     = p0 + link_b[0];
        out[b * 2 + 1] = p1 + link_b[1];
        float* dd = out + 2 * Bc;
        dd[b * 4]     = d0 + lc_b[0];
        dd[b * 4 + 1] = d1 + lc_b[1];
        dd[b * 4 + 2] = d2 + lc_b[2];
        dd[b * 4 + 3] = d3 + lc_b[3];
    }
}

// ---------------- launch ----------------

extern "C" void kernel_launch(void* const* d_in, const int* in_sizes, int n_in,
                              void* d_out, int out_size, void* d_ws, size_t ws_size,
                              hipStream_t stream) {
    const float* x_nodes    = (const float*)d_in[0];
    const int*   edge_index = (const int*)d_in[1];
    const float* W1   = (const float*)d_in[2];
    // d_in[3] = b1 (cancels in BN)
    const float* gamma = (const float*)d_in[4];
    const float* beta  = (const float*)d_in[5];
    const float* W2   = (const float*)d_in[6];
    const float* b2   = (const float*)d_in[7];
    const float* conv_w = (const float*)d_in[8];
    const float* conv_b = (const float*)d_in[9];
    const float* lc_w   = (const float*)d_in[10];
    const float* lc_b   = (const float*)d_in[11];
    const float* link_w = (const float*)d_in[12];
    const float* link_b = (const float*)d_in[13];
    const int* now = (const int*)d_in[14];
    const int* ln  = (const int*)d_in[15];
    const int* rn  = (const int*)d_in[16];
    float* out = (float*)d_out;

    char* base = (char*)d_ws;
    size_t off = 0;
    auto carve = [&](size_t bytes) {
        void* p = base + off;
        off = (off + bytes + 255) & ~(size_t)255;
        return p;
    };
    int*    cnt    = (int*)carve((size_t)Mtot * 4);
    double* stats  = (double*)carve(8 * 8);           // adjacent to cnt: one memset
    int*    tmp    = (int*)carve((size_t)Mtot * 4);
    int*    bsum   = (int*)carve(1024 * 4);
    int*    rstart = (int*)carve((size_t)Mtot * 4);
    int*    cursor = (int*)carve((size_t)Mtot * 4);
    int*    csr    = (int*)carve((size_t)Lc * Ec * 4);
    float*  dis    = (float*)carve((size_t)Mtot * 4);
    float*  s      = (float*)carve((size_t)Mtot * 4);
    float*  cbuf   = (float*)carve(Lc * 72 * 4);
    float*  lsb    = (float*)carve((size_t)Bc * 256 * 4);
    float*  shb    = (float*)carve((size_t)Bc * 256 * 4);
    float*  wT     = (float*)carve((size_t)EDc * EDc * Kc * 4);
    (void)ws_size;

    const int EB = (Ec + 255) / 256;   // 3125

    hipMemsetAsync(cnt, 0, (char*)(stats + 8) - (char*)cnt, stream);
    k_wT<<<1792, 256, 0, stream>>>(conv_w, wT);

    k_count4<<<dim3(EB, Lc), 256, 0, stream>>>(edge_index, cnt);
    k_scan1<<<SB, 256, 0, stream>>>(cnt, tmp, bsum);
    k_scan2<<<1, 1024, 0, stream>>>(bsum, SB);
    k_scan3<<<SB, 256, 0, stream>>>(cnt, tmp, bsum, rstart, cursor, dis);
    k_fill4<<<dim3(EB, Lc), 256, 0, stream>>>(edge_index, cursor, csr);
    k_s_stats4<<<NBK * Lc, 256, 0, stream>>>(rstart, cnt, csr, dis, x_nodes, s, stats);
    k_cvec4<<<1, 256, 0, stream>>>(stats, W1, gamma, cbuf);
    k_embed4<<<Bc, 128, 0, stream>>>(now, ln, rn, rstart, cnt, csr, dis, s,
                                     cbuf, beta, W2, b2, lsb);

    k_conv<<<Bc / NB, 256, 0, stream>>>(lsb, wT, conv_b, shb);
    k_final<<<Bc, 64, 0, stream>>>(lsb, shb, lc_w, lc_b, link_w, link_b, out);
}

// Round 4
// 392.689 us; speedup vs baseline: 4.5504x; 1.8237x over previous
//
#include <hip/hip_runtime.h>
#include <hip/hip_bf16.h>

#define Lc 4
#define Nc 50000
#define Ec 800000
#define Bc 16384
#define EDc 256
#define Kc 7
#define Mtot (Lc * Nc)      // 200000 nodes total
#define NBK 196             // blocks per layer for node-parallel kernels

#define BINW 512            // nodes per bin
#define FB 98               // bins per layer = ceil(50000/512)
#define NBINS (FB * Lc)     // 392
#define CHUNK 8192          // edges per binfill block

// ---------------- binned CSR build, all 4 layers at once ----------------

__global__ void k_bincnt(const int* __restrict__ ei, int* __restrict__ binCnt) {
    int l = blockIdx.y;
    int e0 = blockIdx.x * CHUNK;
    __shared__ int lh[FB];
    if (threadIdx.x < FB) lh[threadIdx.x] = 0;
    __syncthreads();
    const int* dstp = ei + (size_t)l * 2 * Ec + Ec;
#pragma unroll
    for (int it = 0; it < CHUNK / 256; it++) {
        int idx = e0 + it * 256 + threadIdx.x;
        if (idx < Ec) atomicAdd(&lh[dstp[idx] >> 9], 1);
    }
    __syncthreads();
    if (threadIdx.x < FB) {
        int c = lh[threadIdx.x];
        if (c) atomicAdd(&binCnt[l * FB + threadIdx.x], c);
    }
}

__global__ __launch_bounds__(512) void k_binscan(const int* __restrict__ binCnt,
                                                 int* __restrict__ binStart,
                                                 int* __restrict__ binCursor) {
    int i = threadIdx.x;
    int lane = i & 63, wid = i >> 6;
    int v = (i < NBINS) ? binCnt[i] : 0;
    int x = v;
#pragma unroll
    for (int off = 1; off < 64; off <<= 1) {
        int y = __shfl_up(x, off);
        if (lane >= off) x += y;
    }
    __shared__ int ws[8];
    if (lane == 63) ws[wid] = x;
    __syncthreads();
    int carry = 0;
    for (int w = 0; w < wid; w++) carry += ws[w];
    int exc = x - v + carry;
    if (i <= NBINS) binStart[i] = exc;     // binStart[NBINS] = total = Lc*Ec
    if (i < NBINS) binCursor[i] = exc;
}

__global__ void k_binfill(const int* __restrict__ ei, int* __restrict__ binCursor,
                          int* __restrict__ binned) {
    int l = blockIdx.y;
    int e0 = blockIdx.x * CHUNK;
    __shared__ int lh[FB], lcur[FB];
    if (threadIdx.x < FB) lh[threadIdx.x] = 0;
    __syncthreads();
    const int* srcp = ei + (size_t)l * 2 * Ec;
    const int* dstp = srcp + Ec;
#pragma unroll
    for (int it = 0; it < CHUNK / 256; it++) {
        int idx = e0 + it * 256 + threadIdx.x;
        if (idx < Ec) atomicAdd(&lh[dstp[idx] >> 9], 1);
    }
    __syncthreads();
    if (threadIdx.x < FB) {
        int c = lh[threadIdx.x];
        lcur[threadIdx.x] = c ? atomicAdd(&binCursor[l * FB + threadIdx.x], c) : 0;
    }
    __syncthreads();
#pragma unroll
    for (int it = 0; it < CHUNK / 256; it++) {
        int idx = e0 + it * 256 + threadIdx.x;
        if (idx < Ec) {
            int d = dstp[idx], sv = srcp[idx];
            int pos = atomicAdd(&lcur[d >> 9], 1);
            binned[pos] = (sv << 9) | (d & (BINW - 1));
        }
    }
}

// one block per bin: build final CSR segment + per-node cnt/rstart/dis
__global__ __launch_bounds__(512) void k_csr(const int* __restrict__ binStart,
                                             const int* __restrict__ binned,
                                             int* __restrict__ csr,
                                             int* __restrict__ rstart,
                                             int* __restrict__ cnt,
                                             float* __restrict__ dis) {
    int b = blockIdx.x;              // 0..NBINS-1
    int l = b / FB, g = b % FB;
    int rs = binStart[b], re = binStart[b + 1];
    __shared__ int hist[BINW];
    hist[threadIdx.x] = 0;
    __syncthreads();
    for (int i = rs + threadIdx.x; i < re; i += 512)
        atomicAdd(&hist[binned[i] & (BINW - 1)], 1);
    __syncthreads();
    int lane = threadIdx.x & 63, wid = threadIdx.x >> 6;
    int v = hist[threadIdx.x];
    int x = v;
#pragma unroll
    for (int off = 1; off < 64; off <<= 1) {
        int y = __shfl_up(x, off);
        if (lane >= off) x += y;
    }
    __shared__ int ws[8];
    if (lane == 63) ws[wid] = x;
    __syncthreads();
    int carry = 0;
    for (int w = 0; w < wid; w++) carry += ws[w];
    int exc = x - v + carry;         // exclusive prefix within bin
    int n = g * BINW + threadIdx.x;
    int n4 = l * Nc + n;
    if (n < Nc) {
        rstart[n4] = rs + exc;
        cnt[n4] = v;
        dis[n4] = rsqrtf((float)v + 1.0f);   // +1 self loop
    }
    __syncthreads();                 // all reads of hist done
    hist[threadIdx.x] = rs + exc;    // reuse as cursor
    __syncthreads();
    for (int i = rs + threadIdx.x; i < re; i += 512) {
        unsigned p = (unsigned)binned[i];
        int pos = atomicAdd(&hist[p & (BINW - 1)], 1);
        csr[pos] = (int)(p >> 9);
    }
}

// ---------------- scalar aggregation + BN stats (per layer segment) --------

__global__ void k_s_stats4(const int* __restrict__ row_start, const int* __restrict__ cnt,
                           const int* __restrict__ csr, const float* __restrict__ dis,
                           const float* __restrict__ x_nodes, float* __restrict__ s,
                           double* __restrict__ stats) {
    int l = blockIdx.x / NBK;
    int n = (blockIdx.x % NBK) * 256 + threadIdx.x;
    double v = 0.0, v2 = 0.0;
    if (n < Nc) {
        int n4 = l * Nc + n;
        const float* x = x_nodes + (size_t)l * Nc;
        const float* dl = dis + (size_t)l * Nc;
        int st = row_start[n4], en = st + cnt[n4];
        float t = 0.f;
        for (int e = st; e < en; e++) {
            int sv = csr[e];
            t += dl[sv] * x[sv];
        }
        float dn = dl[n];
        float sf = dn * t + dn * dn * x[n];   // neighbors + self loop
        s[n4] = sf;
        v = (double)sf;
        v2 = (double)sf * (double)sf;
    }
    for (int m = 32; m; m >>= 1) { v += __shfl_xor(v, m); v2 += __shfl_xor(v2, m); }
    __shared__ double r0[4], r1[4];
    int wid = threadIdx.x >> 6, lane = threadIdx.x & 63;
    if (lane == 0) { r0[wid] = v; r1[wid] = v2; }
    __syncthreads();
    if (threadIdx.x == 0) {
        atomicAdd(&stats[l * 2 + 0], r0[0] + r0[1] + r0[2] + r0[3]);
        atomicAdd(&stats[l * 2 + 1], r1[0] + r1[1] + r1[2] + r1[3]);
    }
}

__global__ void k_cvec4(const double* __restrict__ stats, const float* __restrict__ W1,
                        const float* __restrict__ gamma, float* __restrict__ cbuf) {
    int l = threadIdx.x >> 6, h = threadIdx.x & 63;  // 256 threads
    double mean = stats[l * 2] / (double)Nc;
    double var = stats[l * 2 + 1] / (double)Nc - mean * mean;
    float w = W1[l * 64 + h];
    cbuf[l * 72 + h] = gamma[l * 64 + h] * w * rsqrtf((float)var * w * w + 1e-5f);
    if (h == 0) cbuf[l * 72 + 64] = (float)mean;
}

// ---------------- per-sample node embedding (all samples, own layer) -------

__global__ __launch_bounds__(128) void k_embed4(const int* __restrict__ now,
        const int* __restrict__ lnn, const int* __restrict__ rnn,
        const int* __restrict__ row_start, const int* __restrict__ cnt,
        const int* __restrict__ csr, const float* __restrict__ dis,
        const float* __restrict__ s, const float* __restrict__ cbuf,
        const float* __restrict__ beta, const float* __restrict__ W2,
        const float* __restrict__ b2, float* __restrict__ lsb) {
    int b = blockIdx.x;
    int l = now[b];
    int side = threadIdx.x >> 6, lane = threadIdx.x & 63;
    int n = side ? rnn[b] : lnn[b];
    int n4 = l * Nc + n;
    float c = cbuf[l * 72 + lane], mu = cbuf[l * 72 + 64], bt = beta[l * 64 + lane];
    const float* dl = dis + (size_t)l * Nc;
    const float* sl = s + (size_t)l * Nc;
    int st = row_start[n4], deg = cnt[n4];
    float a = 0.f;
    for (int base = 0; base < deg; base += 64) {
        int e = base + lane;
        int sv = (e < deg) ? csr[st + e] : 0;
        float nv = (e < deg) ? dl[sv] : 0.f;
        float fv = (e < deg) ? sl[sv] : 0.f;
        int m = min(64, deg - base);
        for (int j = 0; j < m; j++) {
            float nj = __shfl(nv, j);
            float fj = __shfl(fv, j);
            float hv = fmaxf(c * (fj - mu) + bt, 0.f);   // h[src][lane]
            a += nj * hv;
        }
    }
    float dn = dl[n];
    float hself = fmaxf(c * (sl[n] - mu) + bt, 0.f);
    a = dn * a + dn * dn * hself;      // acc_h[lane] for node n
    const float* W2l = W2 + (size_t)l * 64 * 128;
    const float* b2l = b2 + (size_t)l * 128;
    float o0 = b2l[lane], o1 = b2l[lane + 64];
    for (int hh = 0; hh < 64; hh++) {
        float ah = __shfl(a, hh);
        o0 += ah * W2l[hh * 128 + lane];
        o1 += ah * W2l[hh * 128 + lane + 64];
    }
    float* outp = lsb + (size_t)b * 256 + side * 128;
    outp[lane] = o0;
    outp[lane + 64] = o1;
}

// ---------------- tail kernels ----------------

// conv_w [co][ci][k] -> wT [ci][k][co]
__global__ void k_wT(const float* __restrict__ w, float* __restrict__ wT) {
    int i = blockIdx.x * 256 + threadIdx.x; // 256*256*7 = 458752
    wT[(i % (EDc * Kc)) * EDc + i / (EDc * Kc)] = w[i];
}

#define NB 32
__global__ __launch_bounds__(256) void k_conv(const float* __restrict__ ls,
                                              const float* __restrict__ wT,
                                              const float* __restrict__ cb,
                                              float* __restrict__ sh) {
    __shared__ float lss[NB + 6][EDc];
    int b0 = blockIdx.x * NB;
    int co = threadIdx.x;
    for (int r = 0; r < NB + 6; r++) {
        int row = b0 - 3 + r;
        lss[r][co] = (row >= 0 && row < Bc) ? ls[row * EDc + co] : 0.0f;
    }
    __syncthreads();
    float acc[NB];
#pragma unroll
    for (int j = 0; j < NB; j++) acc[j] = 0.0f;
    for (int ci = 0; ci < EDc; ci += 4) {
        float wv[4][Kc];
        const float* wp = wT + (size_t)ci * Kc * EDc + co;
#pragma unroll
        for (int u = 0; u < 4; u++)
#pragma unroll
            for (int k = 0; k < Kc; k++)
                wv[u][k] = wp[(u * Kc + k) * EDc];
#pragma unroll
        for (int rr = 0; rr < NB + 6; rr++) {
            float4 lv = *(const float4*)&lss[rr][ci];
            float lvf[4] = {lv.x, lv.y, lv.z, lv.w};
#pragma unroll
            for (int u = 0; u < 4; u++)
#pragma unroll
                for (int k = 0; k < Kc; k++) {
                    int j = rr - k;
                    if (j >= 0 && j < NB) acc[j] += wv[u][k] * lvf[u];
                }
        }
    }
    float bias = cb[co];
#pragma unroll
    for (int j = 0; j < NB; j++)
        sh[(size_t)(b0 + j) * EDc + co] = fmaxf(acc[j] + bias, 0.0f);
}

__global__ void k_final(const float* __restrict__ ls, const float* __restrict__ sh,
                        const float* __restrict__ lc_w, const float* __restrict__ lc_b,
                        const float* __restrict__ link_w, const float* __restrict__ link_b,
                        float* __restrict__ out) {
    int b = blockIdx.x, lane = threadIdx.x; // 64 threads
    float lsv[4], shv[4];
    float dot = 0.f, nrm = 0.f;
#pragma unroll
    for (int i = 0; i < 4; i++) {
        int ci = lane + i * 64;
        lsv[i] = ls[b * 256 + ci];
        shv[i] = sh[b * 256 + ci];
        dot += lsv[i] * shv[i];
        nrm += shv[i] * shv[i];
    }
    for (int m = 32; m; m >>= 1) { dot += __shfl_xor(dot, m); nrm += __shfl_xor(nrm, m); }
    float coef = dot / (nrm + 1e-12f);
    float p0 = 0.f, p1 = 0.f, d0 = 0.f, d1 = 0.f, d2 = 0.f, d3 = 0.f;
#pragma unroll
    for (int i = 0; i < 4; i++) {
        int ci = lane + i * 64;
        float e = lsv[i] - coef * shv[i] + shv[i];
        p0 += e * link_w[ci * 2];
        p1 += e * link_w[ci * 2 + 1];
        d0 += shv[i] * lc_w[ci * 4];
        d1 += shv[i] * lc_w[ci * 4 + 1];
        d2 += shv[i] * lc_w[ci * 4 + 2];
        d3 += shv[i] * lc_w[ci * 4 + 3];
    }
    for (int m = 32; m; m >>= 1) {
        p0 += __shfl_xor(p0, m); p1 += __shfl_xor(p1, m);
        d0 += __shfl_xor(d0, m); d1 += __shfl_xor(d1, m);
        d2 += __shfl_xor(d2, m); d3 += __shfl_xor(d3, m);
    }
    if (lane == 0) {
        out[b * 2]     = p0 + link_b[0];
        out[b * 2 + 1] = p1 + link_b[1];
        float* dd = out + 2 * Bc;
        dd[b * 4]     = d0 + lc_b[0];
        dd[b * 4 + 1] = d1 + lc_b[1];
        dd[b * 4 + 2] = d2 + lc_b[2];
        dd[b * 4 + 3] = d3 + lc_b[3];
    }
}

// ---------------- launch ----------------

extern "C" void kernel_launch(void* const* d_in, const int* in_sizes, int n_in,
                              void* d_out, int out_size, void* d_ws, size_t ws_size,
                              hipStream_t stream) {
    const float* x_nodes    = (const float*)d_in[0];
    const int*   edge_index = (const int*)d_in[1];
    const float* W1   = (const float*)d_in[2];
    // d_in[3] = b1 (cancels in BN)
    const float* gamma = (const float*)d_in[4];
    const float* beta  = (const float*)d_in[5];
    const float* W2   = (const float*)d_in[6];
    const float* b2   = (const float*)d_in[7];
    const float* conv_w = (const float*)d_in[8];
    const float* conv_b = (const float*)d_in[9];
    const float* lc_w   = (const float*)d_in[10];
    const float* lc_b   = (const float*)d_in[11];
    const float* link_w = (const float*)d_in[12];
    const float* link_b = (const float*)d_in[13];
    const int* now = (const int*)d_in[14];
    const int* ln  = (const int*)d_in[15];
    const int* rn  = (const int*)d_in[16];
    float* out = (float*)d_out;

    char* base = (char*)d_ws;
    size_t off = 0;
    auto carve = [&](size_t bytes) {
        void* p = base + off;
        off = (off + bytes + 255) & ~(size_t)255;
        return p;
    };
    int*    binCnt    = (int*)carve(NBINS * 4);
    double* stats     = (double*)carve(8 * 8);        // adjacent to binCnt: one memset
    int*    binStart  = (int*)carve((NBINS + 1) * 4);
    int*    binCursor = (int*)carve(NBINS * 4);
    int*    binned    = (int*)carve((size_t)Lc * Ec * 4);
    int*    rstart    = (int*)carve((size_t)Mtot * 4);
    int*    cnt       = (int*)carve((size_t)Mtot * 4);
    int*    csr       = (int*)carve((size_t)Lc * Ec * 4);
    float*  dis       = (float*)carve((size_t)Mtot * 4);
    float*  s         = (float*)carve((size_t)Mtot * 4);
    float*  cbuf      = (float*)carve(Lc * 72 * 4);
    float*  lsb       = (float*)carve((size_t)Bc * 256 * 4);
    float*  shb       = (float*)carve((size_t)Bc * 256 * 4);
    float*  wT        = (float*)carve((size_t)EDc * EDc * Kc * 4);
    (void)ws_size;

    const int FBLK = (Ec + CHUNK - 1) / CHUNK;   // 98

    hipMemsetAsync(binCnt, 0, (char*)(stats + 8) - (char*)binCnt, stream);
    k_wT<<<1792, 256, 0, stream>>>(conv_w, wT);

    k_bincnt<<<dim3(FBLK, Lc), 256, 0, stream>>>(edge_index, binCnt);
    k_binscan<<<1, 512, 0, stream>>>(binCnt, binStart, binCursor);
    k_binfill<<<dim3(FBLK, Lc), 256, 0, stream>>>(edge_index, binCursor, binned);
    k_csr<<<NBINS, 512, 0, stream>>>(binStart, binned, csr, rstart, cnt, dis);
    k_s_stats4<<<NBK * Lc, 256, 0, stream>>>(rstart, cnt, csr, dis, x_nodes, s, stats);
    k_cvec4<<<1, 256, 0, stream>>>(stats, W1, gamma, cbuf);
    k_embed4<<<Bc, 128, 0, stream>>>(now, ln, rn, rstart, cnt, csr, dis, s,
                                     cbuf, beta, W2, b2, lsb);

    k_conv<<<Bc / NB, 256, 0, stream>>>(lsb, wT, conv_b, shb);
    k_final<<<Bc, 64, 0, stream>>>(lsb, shb, lc_w, lc_b, link_w, link_b, out);
}

// Round 5
// 260.547 us; speedup vs baseline: 6.8582x; 1.5072x over previous
//
#include <hip/hip_runtime.h>
#include <hip/hip_bf16.h>

#define Lc 4
#define Nc 50000
#define Ec 800000
#define Bc 16384
#define EDc 256
#define Kc 7
#define Mtot (Lc * Nc)      // 200000 nodes total
#define NBK 196             // blocks per layer for node-parallel kernels
#define KDIM (EDc * Kc)     // 1792

#define BINW 512            // nodes per bin
#define FB 98               // bins per layer = ceil(50000/512)
#define NBINS (FB * Lc)     // 392
#define CHUNK 8192          // edges per binfill block

typedef __attribute__((ext_vector_type(8))) short bf16x8;
typedef __attribute__((ext_vector_type(4))) float f32x4;

static __device__ __forceinline__ unsigned short f2bf(float f) {
    unsigned u = __float_as_uint(f);
    unsigned r = (u + 0x7fffu + ((u >> 16) & 1u)) >> 16;
    return (unsigned short)r;
}

// ---------------- binned CSR build, all 4 layers at once ----------------

__global__ void k_bincnt(const int* __restrict__ ei, int* __restrict__ binCnt) {
    int l = blockIdx.y;
    int e0 = blockIdx.x * CHUNK;
    __shared__ int lh[FB];
    if (threadIdx.x < FB) lh[threadIdx.x] = 0;
    __syncthreads();
    const int* dstp = ei + (size_t)l * 2 * Ec + Ec;
#pragma unroll
    for (int it = 0; it < CHUNK / 256; it++) {
        int idx = e0 + it * 256 + threadIdx.x;
        if (idx < Ec) atomicAdd(&lh[dstp[idx] >> 9], 1);
    }
    __syncthreads();
    if (threadIdx.x < FB) {
        int c = lh[threadIdx.x];
        if (c) atomicAdd(&binCnt[l * FB + threadIdx.x], c);
    }
}

__global__ __launch_bounds__(512) void k_binscan(const int* __restrict__ binCnt,
                                                 int* __restrict__ binStart,
                                                 int* __restrict__ binCursor) {
    int i = threadIdx.x;
    int lane = i & 63, wid = i >> 6;
    int v = (i < NBINS) ? binCnt[i] : 0;
    int x = v;
#pragma unroll
    for (int off = 1; off < 64; off <<= 1) {
        int y = __shfl_up(x, off);
        if (lane >= off) x += y;
    }
    __shared__ int ws[8];
    if (lane == 63) ws[wid] = x;
    __syncthreads();
    int carry = 0;
    for (int w = 0; w < wid; w++) carry += ws[w];
    int exc = x - v + carry;
    if (i <= NBINS) binStart[i] = exc;     // binStart[NBINS] = total = Lc*Ec
    if (i < NBINS) binCursor[i] = exc;
}

__global__ void k_binfill(const int* __restrict__ ei, int* __restrict__ binCursor,
                          int* __restrict__ binned) {
    int l = blockIdx.y;
    int e0 = blockIdx.x * CHUNK;
    __shared__ int lh[FB], lcur[FB];
    if (threadIdx.x < FB) lh[threadIdx.x] = 0;
    __syncthreads();
    const int* srcp = ei + (size_t)l * 2 * Ec;
    const int* dstp = srcp + Ec;
#pragma unroll
    for (int it = 0; it < CHUNK / 256; it++) {
        int idx = e0 + it * 256 + threadIdx.x;
        if (idx < Ec) atomicAdd(&lh[dstp[idx] >> 9], 1);
    }
    __syncthreads();
    if (threadIdx.x < FB) {
        int c = lh[threadIdx.x];
        lcur[threadIdx.x] = c ? atomicAdd(&binCursor[l * FB + threadIdx.x], c) : 0;
    }
    __syncthreads();
#pragma unroll
    for (int it = 0; it < CHUNK / 256; it++) {
        int idx = e0 + it * 256 + threadIdx.x;
        if (idx < Ec) {
            int d = dstp[idx], sv = srcp[idx];
            int pos = atomicAdd(&lcur[d >> 9], 1);
            binned[pos] = (sv << 9) | (d & (BINW - 1));
        }
    }
}

// one block per bin: build final CSR segment + per-node cnt/rstart/dis
__global__ __launch_bounds__(512) void k_csr(const int* __restrict__ binStart,
                                             const int* __restrict__ binned,
                                             int* __restrict__ csr,
                                             int* __restrict__ rstart,
                                             int* __restrict__ cnt,
                                             float* __restrict__ dis) {
    int b = blockIdx.x;              // 0..NBINS-1
    int l = b / FB, g = b % FB;
    int rs = binStart[b], re = binStart[b + 1];
    __shared__ int hist[BINW];
    hist[threadIdx.x] = 0;
    __syncthreads();
    for (int i = rs + threadIdx.x; i < re; i += 512)
        atomicAdd(&hist[binned[i] & (BINW - 1)], 1);
    __syncthreads();
    int lane = threadIdx.x & 63, wid = threadIdx.x >> 6;
    int v = hist[threadIdx.x];
    int x = v;
#pragma unroll
    for (int off = 1; off < 64; off <<= 1) {
        int y = __shfl_up(x, off);
        if (lane >= off) x += y;
    }
    __shared__ int ws[8];
    if (lane == 63) ws[wid] = x;
    __syncthreads();
    int carry = 0;
    for (int w = 0; w < wid; w++) carry += ws[w];
    int exc = x - v + carry;         // exclusive prefix within bin
    int n = g * BINW + threadIdx.x;
    int n4 = l * Nc + n;
    if (n < Nc) {
        rstart[n4] = rs + exc;
        cnt[n4] = v;
        dis[n4] = rsqrtf((float)v + 1.0f);   // +1 self loop
    }
    __syncthreads();                 // all reads of hist done
    hist[threadIdx.x] = rs + exc;    // reuse as cursor
    __syncthreads();
    for (int i = rs + threadIdx.x; i < re; i += 512) {
        unsigned p = (unsigned)binned[i];
        int pos = atomicAdd(&hist[p & (BINW - 1)], 1);
        csr[pos] = (int)(p >> 9);
    }
}

// ---------------- scalar aggregation + BN stats (per layer segment) --------

__global__ void k_s_stats4(const int* __restrict__ row_start, const int* __restrict__ cnt,
                           const int* __restrict__ csr, const float* __restrict__ dis,
                           const float* __restrict__ x_nodes, float* __restrict__ s,
                           double* __restrict__ stats) {
    int l = blockIdx.x / NBK;
    int n = (blockIdx.x % NBK) * 256 + threadIdx.x;
    double v = 0.0, v2 = 0.0;
    if (n < Nc) {
        int n4 = l * Nc + n;
        const float* x = x_nodes + (size_t)l * Nc;
        const float* dl = dis + (size_t)l * Nc;
        int st = row_start[n4], en = st + cnt[n4];
        float t = 0.f;
        for (int e = st; e < en; e++) {
            int sv = csr[e];
            t += dl[sv] * x[sv];
        }
        float dn = dl[n];
        float sf = dn * t + dn * dn * x[n];   // neighbors + self loop
        s[n4] = sf;
        v = (double)sf;
        v2 = (double)sf * (double)sf;
    }
    for (int m = 32; m; m >>= 1) { v += __shfl_xor(v, m); v2 += __shfl_xor(v2, m); }
    __shared__ double r0[4], r1[4];
    int wid = threadIdx.x >> 6, lane = threadIdx.x & 63;
    if (lane == 0) { r0[wid] = v; r1[wid] = v2; }
    __syncthreads();
    if (threadIdx.x == 0) {
        atomicAdd(&stats[l * 2 + 0], r0[0] + r0[1] + r0[2] + r0[3]);
        atomicAdd(&stats[l * 2 + 1], r1[0] + r1[1] + r1[2] + r1[3]);
    }
}

__global__ void k_cvec4(const double* __restrict__ stats, const float* __restrict__ W1,
                        const float* __restrict__ gamma, float* __restrict__ cbuf) {
    int l = threadIdx.x >> 6, h = threadIdx.x & 63;  // 256 threads
    double mean = stats[l * 2] / (double)Nc;
    double var = stats[l * 2 + 1] / (double)Nc - mean * mean;
    float w = W1[l * 64 + h];
    cbuf[l * 72 + h] = gamma[l * 64 + h] * w * rsqrtf((float)var * w * w + 1e-5f);
    if (h == 0) cbuf[l * 72 + 64] = (float)mean;
}

// ---------------- per-sample node embedding (all samples, own layer) -------

__global__ __launch_bounds__(128) void k_embed4(const int* __restrict__ now,
        const int* __restrict__ lnn, const int* __restrict__ rnn,
        const int* __restrict__ row_start, const int* __restrict__ cnt,
        const int* __restrict__ csr, const float* __restrict__ dis,
        const float* __restrict__ s, const float* __restrict__ cbuf,
        const float* __restrict__ beta, const float* __restrict__ W2,
        const float* __restrict__ b2, float* __restrict__ lsb,
        unsigned short* __restrict__ lsbh) {
    int b = blockIdx.x;
    int l = now[b];
    int side = threadIdx.x >> 6, lane = threadIdx.x & 63;
    int n = side ? rnn[b] : lnn[b];
    int n4 = l * Nc + n;
    float c = cbuf[l * 72 + lane], mu = cbuf[l * 72 + 64], bt = beta[l * 64 + lane];
    const float* dl = dis + (size_t)l * Nc;
    const float* sl = s + (size_t)l * Nc;
    int st = row_start[n4], deg = cnt[n4];
    float a = 0.f;
    for (int base = 0; base < deg; base += 64) {
        int e = base + lane;
        int sv = (e < deg) ? csr[st + e] : 0;
        float nv = (e < deg) ? dl[sv] : 0.f;
        float fv = (e < deg) ? sl[sv] : 0.f;
        int m = min(64, deg - base);
        for (int j = 0; j < m; j++) {
            float nj = __shfl(nv, j);
            float fj = __shfl(fv, j);
            float hv = fmaxf(c * (fj - mu) + bt, 0.f);   // h[src][lane]
            a += nj * hv;
        }
    }
    float dn = dl[n];
    float hself = fmaxf(c * (sl[n] - mu) + bt, 0.f);
    a = dn * a + dn * dn * hself;      // acc_h[lane] for node n
    const float* W2l = W2 + (size_t)l * 64 * 128;
    const float* b2l = b2 + (size_t)l * 128;
    float o0 = b2l[lane], o1 = b2l[lane + 64];
    for (int hh = 0; hh < 64; hh++) {
        float ah = __shfl(a, hh);
        o0 += ah * W2l[hh * 128 + lane];
        o1 += ah * W2l[hh * 128 + lane + 64];
    }
    size_t obase = (size_t)b * 256 + side * 128;
    lsb[obase + lane] = o0;
    lsb[obase + lane + 64] = o1;
    lsbh[obase + lane] = f2bf(o0);
    lsbh[obase + lane + 64] = f2bf(o1);
}

// ---------------- tail kernels ----------------

// conv_w [co][ci][k] fp32 -> wbt [co][k*256+ci] bf16 (B^T layout for MFMA)
__global__ void k_wbf(const float* __restrict__ w, unsigned short* __restrict__ wbt) {
    int i = blockIdx.x * 256 + threadIdx.x; // 458752
    int co = i / KDIM;
    int r = i % KDIM;
    int ci = r / Kc, k = r % Kc;
    wbt[(size_t)co * KDIM + k * EDc + ci] = f2bf(w[i]);
}

// conv1d as bf16 MFMA GEMM: M=Bc rows(b), N=256 cols(co), K=1792 (k-major, ci-minor)
// A'[b][kk] = ls[b + k - 3][ci] read direct from global lsbh (zero-pad OOB rows)
// B'[kk][co] from wbt[co][kk] (B^T, 8 contiguous kk per lane)
__global__ __launch_bounds__(512) void k_convmma(const unsigned short* __restrict__ lsbh,
                                                 const unsigned short* __restrict__ wbt,
                                                 const float* __restrict__ cb,
                                                 float* __restrict__ sh) {
    int b0 = blockIdx.x * 64;
    int wid = threadIdx.x >> 6, lane = threadIdx.x & 63;
    int wm = wid >> 2, wn = wid & 3;          // 2 x 4 wave grid
    int lrow = lane & 15, lg = lane >> 4;     // frag 16-index and k-group
    f32x4 acc[2][4] = {};

    int coBase = wn * 64 + lrow;
    const unsigned short* wrow = wbt + (size_t)coBase * KDIM + lg * 8;
    int arowBase = b0 + wm * 32 + lrow - 3;
    const bf16x8 zerov = {0, 0, 0, 0, 0, 0, 0, 0};

    for (int t = 0; t < 56; t++) {
        int k = t >> 3, ci0 = (t & 7) << 5;
        bf16x8 a[2], bfr[4];
#pragma unroll
        for (int mi = 0; mi < 2; mi++) {
            int row = arowBase + mi * 16 + k;
            a[mi] = ((unsigned)row < (unsigned)Bc)
                  ? *(const bf16x8*)(lsbh + (size_t)row * EDc + ci0 + lg * 8)
                  : zerov;
        }
#pragma unroll
        for (int ni = 0; ni < 4; ni++)
            bfr[ni] = *(const bf16x8*)(wrow + (size_t)ni * 16 * KDIM + t * 32);
#pragma unroll
        for (int mi = 0; mi < 2; mi++)
#pragma unroll
            for (int ni = 0; ni < 4; ni++)
                acc[mi][ni] = __builtin_amdgcn_mfma_f32_16x16x32_bf16(
                    a[mi], bfr[ni], acc[mi][ni], 0, 0, 0);
    }

#pragma unroll
    for (int mi = 0; mi < 2; mi++) {
        int rbase = b0 + wm * 32 + mi * 16 + lg * 4;
#pragma unroll
        for (int ni = 0; ni < 4; ni++) {
            int co = wn * 64 + ni * 16 + lrow;
            float bias = cb[co];
#pragma unroll
            for (int r = 0; r < 4; r++)
                sh[(size_t)(rbase + r) * EDc + co] = fmaxf(acc[mi][ni][r] + bias, 0.0f);
        }
    }
}

__global__ void k_final(const float* __restrict__ ls, const float* __restrict__ sh,
                        const float* __restrict__ lc_w, const float* __restrict__ lc_b,
                        const float* __restrict__ link_w, const float* __restrict__ link_b,
                        float* __restrict__ out) {
    int b = blockIdx.x, lane = threadIdx.x; // 64 threads
    float lsv[4], shv[4];
    float dot = 0.f, nrm = 0.f;
#pragma unroll
    for (int i = 0; i < 4; i++) {
        int ci = lane + i * 64;
        lsv[i] = ls[b * 256 + ci];
        shv[i] = sh[b * 256 + ci];
        dot += lsv[i] * shv[i];
        nrm += shv[i] * shv[i];
    }
    for (int m = 32; m; m >>= 1) { dot += __shfl_xor(dot, m); nrm += __shfl_xor(nrm, m); }
    float coef = dot / (nrm + 1e-12f);
    float p0 = 0.f, p1 = 0.f, d0 = 0.f, d1 = 0.f, d2 = 0.f, d3 = 0.f;
#pragma unroll
    for (int i = 0; i < 4; i++) {
        int ci = lane + i * 64;
        float e = lsv[i] - coef * shv[i] + shv[i];
        p0 += e * link_w[ci * 2];
        p1 += e * link_w[ci * 2 + 1];
        d0 += shv[i] * lc_w[ci * 4];
        d1 += shv[i] * lc_w[ci * 4 + 1];
        d2 += shv[i] * lc_w[ci * 4 + 2];
        d3 += shv[i] * lc_w[ci * 4 + 3];
    }
    for (int m = 32; m; m >>= 1) {
        p0 += __shfl_xor(p0, m); p1 += __shfl_xor(p1, m);
        d0 += __shfl_xor(d0, m); d1 += __shfl_xor(d1, m);
        d2 += __shfl_xor(d2, m); d3 += __shfl_xor(d3, m);
    }
    if (lane == 0) {
        out[b * 2]     = p0 + link_b[0];
        out[b * 2 + 1] = p1 + link_b[1];
        float* dd = out + 2 * Bc;
        dd[b * 4]     = d0 + lc_b[0];
        dd[b * 4 + 1] = d1 + lc_b[1];
        dd[b * 4 + 2] = d2 + lc_b[2];
        dd[b * 4 + 3] = d3 + lc_b[3];
    }
}

// ---------------- launch ----------------

extern "C" void kernel_launch(void* const* d_in, const int* in_sizes, int n_in,
                              void* d_out, int out_size, void* d_ws, size_t ws_size,
                              hipStream_t stream) {
    const float* x_nodes    = (const float*)d_in[0];
    const int*   edge_index = (const int*)d_in[1];
    const float* W1   = (const float*)d_in[2];
    // d_in[3] = b1 (cancels in BN)
    const float* gamma = (const float*)d_in[4];
    const float* beta  = (const float*)d_in[5];
    const float* W2   = (const float*)d_in[6];
    const float* b2   = (const float*)d_in[7];
    const float* conv_w = (const float*)d_in[8];
    const float* conv_b = (const float*)d_in[9];
    const float* lc_w   = (const float*)d_in[10];
    const float* lc_b   = (const float*)d_in[11];
    const float* link_w = (const float*)d_in[12];
    const float* link_b = (const float*)d_in[13];
    const int* now = (const int*)d_in[14];
    const int* ln  = (const int*)d_in[15];
    const int* rn  = (const int*)d_in[16];
    float* out = (float*)d_out;

    char* base = (char*)d_ws;
    size_t off = 0;
    auto carve = [&](size_t bytes) {
        void* p = base + off;
        off = (off + bytes + 255) & ~(size_t)255;
        return p;
    };
    int*    binCnt    = (int*)carve(NBINS * 4);
    double* stats     = (double*)carve(8 * 8);        // adjacent to binCnt: one memset
    int*    binStart  = (int*)carve((NBINS + 1) * 4);
    int*    binCursor = (int*)carve(NBINS * 4);
    int*    binned    = (int*)carve((size_t)Lc * Ec * 4);
    int*    rstart    = (int*)carve((size_t)Mtot * 4);
    int*    cnt       = (int*)carve((size_t)Mtot * 4);
    int*    csr       = (int*)carve((size_t)Lc * Ec * 4);
    float*  dis       = (float*)carve((size_t)Mtot * 4);
    float*  s         = (float*)carve((size_t)Mtot * 4);
    float*  cbuf      = (float*)carve(Lc * 72 * 4);
    float*  lsb       = (float*)carve((size_t)Bc * 256 * 4);
    float*  shb       = (float*)carve((size_t)Bc * 256 * 4);
    unsigned short* lsbh = (unsigned short*)carve((size_t)Bc * 256 * 2);
    unsigned short* wbt  = (unsigned short*)carve((size_t)EDc * KDIM * 2);
    (void)ws_size;

    const int FBLK = (Ec + CHUNK - 1) / CHUNK;   // 98

    hipMemsetAsync(binCnt, 0, (char*)(stats + 8) - (char*)binCnt, stream);
    k_wbf<<<1792, 256, 0, stream>>>(conv_w, wbt);

    k_bincnt<<<dim3(FBLK, Lc), 256, 0, stream>>>(edge_index, binCnt);
    k_binscan<<<1, 512, 0, stream>>>(binCnt, binStart, binCursor);
    k_binfill<<<dim3(FBLK, Lc), 256, 0, stream>>>(edge_index, binCursor, binned);
    k_csr<<<NBINS, 512, 0, stream>>>(binStart, binned, csr, rstart, cnt, dis);
    k_s_stats4<<<NBK * Lc, 256, 0, stream>>>(rstart, cnt, csr, dis, x_nodes, s, stats);
    k_cvec4<<<1, 256, 0, stream>>>(stats, W1, gamma, cbuf);
    k_embed4<<<Bc, 128, 0, stream>>>(now, ln, rn, rstart, cnt, csr, dis, s,
                                     cbuf, beta, W2, b2, lsb, lsbh);

    k_convmma<<<Bc / 64, 512, 0, stream>>>(lsbh, wbt, conv_b, shb);
    k_final<<<Bc, 64, 0, stream>>>(lsb, shb, lc_w, lc_b, link_w, link_b, out);
}

// Round 7
// 238.111 us; speedup vs baseline: 7.5044x; 1.0942x over previous
//
#include <hip/hip_runtime.h>
#include <hip/hip_bf16.h>

#define Lc 4
#define Nc 50000
#define Ec 800000
#define Bc 16384
#define EDc 256
#define Kc 7
#define Mtot (Lc * Nc)      // 200000 nodes total
#define NBK 196             // blocks per layer for node-parallel kernels
#define KDIM (EDc * Kc)     // 1792

#define BINW 512            // nodes per bin
#define FB 98               // bins per layer = ceil(50000/512)
#define NBINS (FB * Lc)     // 392
#define CHUNK 8192          // edges per binfill block

typedef __attribute__((ext_vector_type(8))) short bf16x8;
typedef __attribute__((ext_vector_type(4))) float f32x4;

static __device__ __forceinline__ unsigned short f2bf(float f) {
    unsigned u = __float_as_uint(f);
    unsigned r = (u + 0x7fffu + ((u >> 16) & 1u)) >> 16;
    return (unsigned short)r;
}

// ---------------- binned CSR build, all 4 layers at once ----------------

__global__ void k_bincnt(const int* __restrict__ ei, int* __restrict__ binCnt) {
    int l = blockIdx.y;
    int e0 = blockIdx.x * CHUNK;
    __shared__ int lh[FB];
    if (threadIdx.x < FB) lh[threadIdx.x] = 0;
    __syncthreads();
    const int* dstp = ei + (size_t)l * 2 * Ec + Ec;
#pragma unroll
    for (int it = 0; it < CHUNK / 256; it++) {
        int idx = e0 + it * 256 + threadIdx.x;
        if (idx < Ec) atomicAdd(&lh[dstp[idx] >> 9], 1);
    }
    __syncthreads();
    if (threadIdx.x < FB) {
        int c = lh[threadIdx.x];
        if (c) atomicAdd(&binCnt[l * FB + threadIdx.x], c);
    }
}

__global__ __launch_bounds__(512) void k_binscan(const int* __restrict__ binCnt,
                                                 int* __restrict__ binStart,
                                                 int* __restrict__ binCursor) {
    int i = threadIdx.x;
    int lane = i & 63, wid = i >> 6;
    int v = (i < NBINS) ? binCnt[i] : 0;
    int x = v;
#pragma unroll
    for (int off = 1; off < 64; off <<= 1) {
        int y = __shfl_up(x, off);
        if (lane >= off) x += y;
    }
    __shared__ int ws[8];
    if (lane == 63) ws[wid] = x;
    __syncthreads();
    int carry = 0;
    for (int w = 0; w < wid; w++) carry += ws[w];
    int exc = x - v + carry;
    if (i <= NBINS) binStart[i] = exc;     // binStart[NBINS] = total = Lc*Ec
    if (i < NBINS) binCursor[i] = exc;
}

__global__ void k_binfill(const int* __restrict__ ei, int* __restrict__ binCursor,
                          int* __restrict__ binned) {
    int l = blockIdx.y;
    int e0 = blockIdx.x * CHUNK;
    __shared__ int lh[FB], lcur[FB];
    if (threadIdx.x < FB) lh[threadIdx.x] = 0;
    __syncthreads();
    const int* srcp = ei + (size_t)l * 2 * Ec;
    const int* dstp = srcp + Ec;
#pragma unroll
    for (int it = 0; it < CHUNK / 256; it++) {
        int idx = e0 + it * 256 + threadIdx.x;
        if (idx < Ec) atomicAdd(&lh[dstp[idx] >> 9], 1);
    }
    __syncthreads();
    if (threadIdx.x < FB) {
        int c = lh[threadIdx.x];
        lcur[threadIdx.x] = c ? atomicAdd(&binCursor[l * FB + threadIdx.x], c) : 0;
    }
    __syncthreads();
#pragma unroll
    for (int it = 0; it < CHUNK / 256; it++) {
        int idx = e0 + it * 256 + threadIdx.x;
        if (idx < Ec) {
            int d = dstp[idx], sv = srcp[idx];
            int pos = atomicAdd(&lcur[d >> 9], 1);
            binned[pos] = (sv << 9) | (d & (BINW - 1));
        }
    }
}

// one block per bin: build final CSR segment + per-node cnt/rstart/dis
__global__ __launch_bounds__(512) void k_csr(const int* __restrict__ binStart,
                                             const int* __restrict__ binned,
                                             int* __restrict__ csr,
                                             int* __restrict__ rstart,
                                             int* __restrict__ cnt,
                                             float* __restrict__ dis) {
    int b = blockIdx.x;              // 0..NBINS-1
    int l = b / FB, g = b % FB;
    int rs = binStart[b], re = binStart[b + 1];
    __shared__ int hist[BINW];
    hist[threadIdx.x] = 0;
    __syncthreads();
    for (int i = rs + threadIdx.x; i < re; i += 512)
        atomicAdd(&hist[binned[i] & (BINW - 1)], 1);
    __syncthreads();
    int lane = threadIdx.x & 63, wid = threadIdx.x >> 6;
    int v = hist[threadIdx.x];
    int x = v;
#pragma unroll
    for (int off = 1; off < 64; off <<= 1) {
        int y = __shfl_up(x, off);
        if (lane >= off) x += y;
    }
    __shared__ int ws[8];
    if (lane == 63) ws[wid] = x;
    __syncthreads();
    int carry = 0;
    for (int w = 0; w < wid; w++) carry += ws[w];
    int exc = x - v + carry;         // exclusive prefix within bin
    int n = g * BINW + threadIdx.x;
    int n4 = l * Nc + n;
    if (n < Nc) {
        rstart[n4] = rs + exc;
        cnt[n4] = v;
        dis[n4] = rsqrtf((float)v + 1.0f);   // +1 self loop
    }
    __syncthreads();                 // all reads of hist done
    hist[threadIdx.x] = rs + exc;    // reuse as cursor
    __syncthreads();
    for (int i = rs + threadIdx.x; i < re; i += 512) {
        unsigned p = (unsigned)binned[i];
        int pos = atomicAdd(&hist[p & (BINW - 1)], 1);
        csr[pos] = (int)(p >> 9);
    }
}

// ---------------- scalar aggregation + BN stats (per layer segment) --------

__global__ void k_s_stats4(const int* __restrict__ row_start, const int* __restrict__ cnt,
                           const int* __restrict__ csr, const float* __restrict__ dis,
                           const float* __restrict__ x_nodes, float* __restrict__ s,
                           double* __restrict__ stats) {
    int l = blockIdx.x / NBK;
    int n = (blockIdx.x % NBK) * 256 + threadIdx.x;
    double v = 0.0, v2 = 0.0;
    if (n < Nc) {
        int n4 = l * Nc + n;
        const float* x = x_nodes + (size_t)l * Nc;
        const float* dl = dis + (size_t)l * Nc;
        int st = row_start[n4], en = st + cnt[n4];
        float t = 0.f;
        for (int e = st; e < en; e++) {
            int sv = csr[e];
            t += dl[sv] * x[sv];
        }
        float dn = dl[n];
        float sf = dn * t + dn * dn * x[n];   // neighbors + self loop
        s[n4] = sf;
        v = (double)sf;
        v2 = (double)sf * (double)sf;
    }
    for (int m = 32; m; m >>= 1) { v += __shfl_xor(v, m); v2 += __shfl_xor(v2, m); }
    __shared__ double r0[4], r1[4];
    int wid = threadIdx.x >> 6, lane = threadIdx.x & 63;
    if (lane == 0) { r0[wid] = v; r1[wid] = v2; }
    __syncthreads();
    if (threadIdx.x == 0) {
        atomicAdd(&stats[l * 2 + 0], r0[0] + r0[1] + r0[2] + r0[3]);
        atomicAdd(&stats[l * 2 + 1], r1[0] + r1[1] + r1[2] + r1[3]);
    }
}

__global__ void k_cvec4(const double* __restrict__ stats, const float* __restrict__ W1,
                        const float* __restrict__ gamma, float* __restrict__ cbuf) {
    int l = threadIdx.x >> 6, h = threadIdx.x & 63;  // 256 threads
    double mean = stats[l * 2] / (double)Nc;
    double var = stats[l * 2 + 1] / (double)Nc - mean * mean;
    float w = W1[l * 64 + h];
    cbuf[l * 72 + h] = gamma[l * 64 + h] * w * rsqrtf((float)var * w * w + 1e-5f);
    if (h == 0) cbuf[l * 72 + 64] = (float)mean;
}

// ---------------- per-sample node embedding (all samples, own layer) -------

__global__ __launch_bounds__(128) void k_embed4(const int* __restrict__ now,
        const int* __restrict__ lnn, const int* __restrict__ rnn,
        const int* __restrict__ row_start, const int* __restrict__ cnt,
        const int* __restrict__ csr, const float* __restrict__ dis,
        const float* __restrict__ s, const float* __restrict__ cbuf,
        const float* __restrict__ beta, const float* __restrict__ W2,
        const float* __restrict__ b2, float* __restrict__ lsb,
        unsigned short* __restrict__ lsbh) {
    int b = blockIdx.x;
    int l = now[b];
    int side = threadIdx.x >> 6, lane = threadIdx.x & 63;
    int n = side ? rnn[b] : lnn[b];
    int n4 = l * Nc + n;
    float c = cbuf[l * 72 + lane], mu = cbuf[l * 72 + 64], bt = beta[l * 64 + lane];
    const float* dl = dis + (size_t)l * Nc;
    const float* sl = s + (size_t)l * Nc;
    int st = row_start[n4], deg = cnt[n4];
    float a = 0.f;
    for (int base = 0; base < deg; base += 64) {
        int e = base + lane;
        int sv = (e < deg) ? csr[st + e] : 0;
        float nv = (e < deg) ? dl[sv] : 0.f;
        float fv = (e < deg) ? sl[sv] : 0.f;
        int m = min(64, deg - base);
        for (int j = 0; j < m; j++) {
            float nj = __shfl(nv, j);
            float fj = __shfl(fv, j);
            float hv = fmaxf(c * (fj - mu) + bt, 0.f);   // h[src][lane]
            a += nj * hv;
        }
    }
    float dn = dl[n];
    float hself = fmaxf(c * (sl[n] - mu) + bt, 0.f);
    a = dn * a + dn * dn * hself;      // acc_h[lane] for node n
    const float* W2l = W2 + (size_t)l * 64 * 128;
    const float* b2l = b2 + (size_t)l * 128;
    float o0 = b2l[lane], o1 = b2l[lane + 64];
    for (int hh = 0; hh < 64; hh++) {
        float ah = __shfl(a, hh);
        o0 += ah * W2l[hh * 128 + lane];
        o1 += ah * W2l[hh * 128 + lane + 64];
    }
    size_t obase = (size_t)b * 256 + side * 128;
    lsb[obase + lane] = o0;
    lsb[obase + lane + 64] = o1;
    lsbh[obase + lane] = f2bf(o0);
    lsbh[obase + lane + 64] = f2bf(o1);
}

// ---------------- tail kernels ----------------

// conv_w [co][ci][k] fp32 -> wbt [co][k*256+ci] bf16 (B^T layout for MFMA)
__global__ void k_wbf(const float* __restrict__ w, unsigned short* __restrict__ wbt) {
    int i = blockIdx.x * 256 + threadIdx.x; // 458752
    int co = i / KDIM;
    int r = i % KDIM;
    int ci = r / Kc, k = r % Kc;
    wbt[(size_t)co * KDIM + k * EDc + ci] = f2bf(w[i]);
}

// conv1d as bf16 MFMA GEMM: M=Bc rows(b), N=256 cols(co), K=1792 (k-major, ci-minor)
// Block: 32 rows, 8 waves 1x8 (wave = 32 rows x 32 co). A window staged in LDS
// (XOR-swizzled); B streamed from global.
// NOTE: the swizzle XOR must be applied to the FULL column byte offset
// (lg*16 + tt*64) — XOR-then-add corrupts addresses when swz bit6 carries.
__global__ __launch_bounds__(512) void k_convmma(const unsigned short* __restrict__ lsbh,
                                                 const unsigned short* __restrict__ wbt,
                                                 const float* __restrict__ cb,
                                                 float* __restrict__ sh) {
    __shared__ unsigned short lsa[38 * EDc];   // 19456 B
    int b0 = blockIdx.x * 32;
    int wid = threadIdx.x >> 6, lane = threadIdx.x & 63;
    int lrow = lane & 15, lg = lane >> 4;

    // stage A rows [b0-3, b0+35) -> LDS, swizzle byte = (r*512 + col) ^ ((r&7)<<4)
    for (int idx = threadIdx.x; idx < 38 * 32; idx += 512) {
        int r = idx >> 5, c = idx & 31;
        int grow = b0 - 3 + r;
        uint4 v = make_uint4(0u, 0u, 0u, 0u);
        if ((unsigned)grow < (unsigned)Bc)
            v = *(const uint4*)(lsbh + (size_t)grow * EDc + c * 8);
        int byte = (r * 512 + c * 16) ^ ((r & 7) << 4);
        *(uint4*)((char*)lsa + byte) = v;
    }
    __syncthreads();

    const unsigned short* w0 = wbt + (size_t)(wid * 32 + lrow) * KDIM + lg * 8;
    const unsigned short* w1 = w0 + (size_t)16 * KDIM;

    f32x4 acc[2][2] = {};

    for (int k = 0; k < Kc; k++) {
        int l0 = lrow + k, l1 = l0 + 16;
        int base0 = l0 * 512, swz0 = (l0 & 7) << 4;
        int base1 = l1 * 512, swz1 = (l1 & 7) << 4;
        const unsigned short* pb = w0 + k * 256;
        const unsigned short* pb1 = w1 + k * 256;
#pragma unroll
        for (int tt = 0; tt < 8; tt++) {
            int col = lg * 16 + tt * 64;
            bf16x8 a0 = *(const bf16x8*)((const char*)lsa + base0 + (col ^ swz0));
            bf16x8 a1 = *(const bf16x8*)((const char*)lsa + base1 + (col ^ swz1));
            bf16x8 bf0 = *(const bf16x8*)(pb + tt * 32);
            bf16x8 bf1 = *(const bf16x8*)(pb1 + tt * 32);
            acc[0][0] = __builtin_amdgcn_mfma_f32_16x16x32_bf16(a0, bf0, acc[0][0], 0, 0, 0);
            acc[0][1] = __builtin_amdgcn_mfma_f32_16x16x32_bf16(a0, bf1, acc[0][1], 0, 0, 0);
            acc[1][0] = __builtin_amdgcn_mfma_f32_16x16x32_bf16(a1, bf0, acc[1][0], 0, 0, 0);
            acc[1][1] = __builtin_amdgcn_mfma_f32_16x16x32_bf16(a1, bf1, acc[1][1], 0, 0, 0);
        }
    }

#pragma unroll
    for (int mi = 0; mi < 2; mi++) {
        int rbase = b0 + mi * 16 + lg * 4;
#pragma unroll
        for (int ni = 0; ni < 2; ni++) {
            int co = wid * 32 + ni * 16 + lrow;
            float bias = cb[co];
#pragma unroll
            for (int r = 0; r < 4; r++)
                sh[(size_t)(rbase + r) * EDc + co] = fmaxf(acc[mi][ni][r] + bias, 0.0f);
        }
    }
}

__global__ void k_final(const float* __restrict__ ls, const float* __restrict__ sh,
                        const float* __restrict__ lc_w, const float* __restrict__ lc_b,
                        const float* __restrict__ link_w, const float* __restrict__ link_b,
                        float* __restrict__ out) {
    int b = blockIdx.x, lane = threadIdx.x; // 64 threads
    float lsv[4], shv[4];
    float dot = 0.f, nrm = 0.f;
#pragma unroll
    for (int i = 0; i < 4; i++) {
        int ci = lane + i * 64;
        lsv[i] = ls[b * 256 + ci];
        shv[i] = sh[b * 256 + ci];
        dot += lsv[i] * shv[i];
        nrm += shv[i] * shv[i];
    }
    for (int m = 32; m; m >>= 1) { dot += __shfl_xor(dot, m); nrm += __shfl_xor(nrm, m); }
    float coef = dot / (nrm + 1e-12f);
    float p0 = 0.f, p1 = 0.f, d0 = 0.f, d1 = 0.f, d2 = 0.f, d3 = 0.f;
#pragma unroll
    for (int i = 0; i < 4; i++) {
        int ci = lane + i * 64;
        float e = lsv[i] - coef * shv[i] + shv[i];
        p0 += e * link_w[ci * 2];
        p1 += e * link_w[ci * 2 + 1];
        d0 += shv[i] * lc_w[ci * 4];
        d1 += shv[i] * lc_w[ci * 4 + 1];
        d2 += shv[i] * lc_w[ci * 4 + 2];
        d3 += shv[i] * lc_w[ci * 4 + 3];
    }
    for (int m = 32; m; m >>= 1) {
        p0 += __shfl_xor(p0, m); p1 += __shfl_xor(p1, m);
        d0 += __shfl_xor(d0, m); d1 += __shfl_xor(d1, m);
        d2 += __shfl_xor(d2, m); d3 += __shfl_xor(d3, m);
    }
    if (lane == 0) {
        out[b * 2]     = p0 + link_b[0];
        out[b * 2 + 1] = p1 + link_b[1];
        float* dd = out + 2 * Bc;
        dd[b * 4]     = d0 + lc_b[0];
        dd[b * 4 + 1] = d1 + lc_b[1];
        dd[b * 4 + 2] = d2 + lc_b[2];
        dd[b * 4 + 3] = d3 + lc_b[3];
    }
}

// ---------------- launch ----------------

extern "C" void kernel_launch(void* const* d_in, const int* in_sizes, int n_in,
                              void* d_out, int out_size, void* d_ws, size_t ws_size,
                              hipStream_t stream) {
    const float* x_nodes    = (const float*)d_in[0];
    const int*   edge_index = (const int*)d_in[1];
    const float* W1   = (const float*)d_in[2];
    // d_in[3] = b1 (cancels in BN)
    const float* gamma = (const float*)d_in[4];
    const float* beta  = (const float*)d_in[5];
    const float* W2   = (const float*)d_in[6];
    const float* b2   = (const float*)d_in[7];
    const float* conv_w = (const float*)d_in[8];
    const float* conv_b = (const float*)d_in[9];
    const float* lc_w   = (const float*)d_in[10];
    const float* lc_b   = (const float*)d_in[11];
    const float* link_w = (const float*)d_in[12];
    const float* link_b = (const float*)d_in[13];
    const int* now = (const int*)d_in[14];
    const int* ln  = (const int*)d_in[15];
    const int* rn  = (const int*)d_in[16];
    float* out = (float*)d_out;

    char* base = (char*)d_ws;
    size_t off = 0;
    auto carve = [&](size_t bytes) {
        void* p = base + off;
        off = (off + bytes + 255) & ~(size_t)255;
        return p;
    };
    int*    binCnt    = (int*)carve(NBINS * 4);
    double* stats     = (double*)carve(8 * 8);        // adjacent to binCnt: one memset
    int*    binStart  = (int*)carve((NBINS + 1) * 4);
    int*    binCursor = (int*)carve(NBINS * 4);
    int*    binned    = (int*)carve((size_t)Lc * Ec * 4);
    int*    rstart    = (int*)carve((size_t)Mtot * 4);
    int*    cnt       = (int*)carve((size_t)Mtot * 4);
    int*    csr       = (int*)carve((size_t)Lc * Ec * 4);
    float*  dis       = (float*)carve((size_t)Mtot * 4);
    float*  s         = (float*)carve((size_t)Mtot * 4);
    float*  cbuf      = (float*)carve(Lc * 72 * 4);
    float*  lsb       = (float*)carve((size_t)Bc * 256 * 4);
    float*  shb       = (float*)carve((size_t)Bc * 256 * 4);
    unsigned short* lsbh = (unsigned short*)carve((size_t)Bc * 256 * 2);
    unsigned short* wbt  = (unsigned short*)carve((size_t)EDc * KDIM * 2);
    (void)ws_size;

    const int FBLK = (Ec + CHUNK - 1) / CHUNK;   // 98

    hipMemsetAsync(binCnt, 0, (char*)(stats + 8) - (char*)binCnt, stream);
    k_wbf<<<1792, 256, 0, stream>>>(conv_w, wbt);

    k_bincnt<<<dim3(FBLK, Lc), 256, 0, stream>>>(edge_index, binCnt);
    k_binscan<<<1, 512, 0, stream>>>(binCnt, binStart, binCursor);
    k_binfill<<<dim3(FBLK, Lc), 256, 0, stream>>>(edge_index, binCursor, binned);
    k_csr<<<NBINS, 512, 0, stream>>>(binStart, binned, csr, rstart, cnt, dis);
    k_s_stats4<<<NBK * Lc, 256, 0, stream>>>(rstart, cnt, csr, dis, x_nodes, s, stats);
    k_cvec4<<<1, 256, 0, stream>>>(stats, W1, gamma, cbuf);
    k_embed4<<<Bc, 128, 0, stream>>>(now, ln, rn, rstart, cnt, csr, dis, s,
                                     cbuf, beta, W2, b2, lsb, lsbh);

    k_convmma<<<Bc / 32, 512, 0, stream>>>(lsbh, wbt, conv_b, shb);
    k_final<<<Bc, 64, 0, stream>>>(lsb, shb, lc_w, lc_b, link_w, link_b, out);
}

// Round 8
// 210.060 us; speedup vs baseline: 8.5065x; 1.1335x over previous
//
#include <hip/hip_runtime.h>
#include <hip/hip_bf16.h>

#define Lc 4
#define Nc 50000
#define Ec 800000
#define Bc 16384
#define EDc 256
#define Kc 7
#define Mtot (Lc * Nc)      // 200000 nodes total
#define NBK 196             // blocks per layer for node-parallel kernels
#define KDIM (EDc * Kc)     // 1792

#define BINW 512            // nodes per bin
#define FB 98               // bins per layer = ceil(50000/512)
#define NBINS (FB * Lc)     // 392
#define CAPc 12288          // fixed bin capacity (mean 8192, sigma ~90)
#define CHUNK 8192          // edges per binfill block

typedef __attribute__((ext_vector_type(8))) short bf16x8;
typedef __attribute__((ext_vector_type(4))) float f32x4;

static __device__ __forceinline__ unsigned short f2bf(float f) {
    unsigned u = __float_as_uint(f);
    unsigned r = (u + 0x7fffu + ((u >> 16) & 1u)) >> 16;
    return (unsigned short)r;
}

// ---------------- binned edge sort (fixed-capacity bins, no scan) ----------

__global__ void k_binfill(const int* __restrict__ ei, int* __restrict__ binCursor,
                          int* __restrict__ binned) {
    int l = blockIdx.y;
    int e0 = blockIdx.x * CHUNK;
    __shared__ int lh[FB], lcur[FB];
    if (threadIdx.x < FB) lh[threadIdx.x] = 0;
    __syncthreads();
    const int* srcp = ei + (size_t)l * 2 * Ec;
    const int* dstp = srcp + Ec;
#pragma unroll
    for (int it = 0; it < CHUNK / 256; it++) {
        int idx = e0 + it * 256 + threadIdx.x;
        if (idx < Ec) atomicAdd(&lh[dstp[idx] >> 9], 1);
    }
    __syncthreads();
    if (threadIdx.x < FB) {
        int c = lh[threadIdx.x];
        int bin = l * FB + threadIdx.x;
        int st = c ? atomicAdd(&binCursor[bin], c) : 0;
        lcur[threadIdx.x] = bin * CAPc + min(st, CAPc);
        lh[threadIdx.x] = bin * CAPc + CAPc;    // reuse as limit
    }
    __syncthreads();
#pragma unroll
    for (int it = 0; it < CHUNK / 256; it++) {
        int idx = e0 + it * 256 + threadIdx.x;
        if (idx < Ec) {
            int d = dstp[idx], sv = srcp[idx];
            int t = d >> 9;
            int pos = atomicAdd(&lcur[t], 1);
            if (pos < lh[t]) binned[pos] = (sv << 9) | (d & (BINW - 1));
        }
    }
}

// one block per bin: build final CSR segment + per-node cnt/rstart/dis
__global__ __launch_bounds__(512) void k_csr(const int* __restrict__ binCnt,
                                             const int* __restrict__ binned,
                                             int* __restrict__ csr,
                                             int* __restrict__ rstart,
                                             int* __restrict__ cnt,
                                             float* __restrict__ dis) {
    int b = blockIdx.x;              // 0..NBINS-1
    int l = b / FB, g = b % FB;
    int rs = b * CAPc;
    int cntb = binCnt[b];
    if (cntb > CAPc) cntb = CAPc;
    int re = rs + cntb;
    __shared__ int hist[BINW];
    hist[threadIdx.x] = 0;
    __syncthreads();
    for (int i = rs + threadIdx.x; i < re; i += 512)
        atomicAdd(&hist[binned[i] & (BINW - 1)], 1);
    __syncthreads();
    int lane = threadIdx.x & 63, wid = threadIdx.x >> 6;
    int v = hist[threadIdx.x];
    int x = v;
#pragma unroll
    for (int off = 1; off < 64; off <<= 1) {
        int y = __shfl_up(x, off);
        if (lane >= off) x += y;
    }
    __shared__ int ws[8];
    if (lane == 63) ws[wid] = x;
    __syncthreads();
    int carry = 0;
    for (int w = 0; w < wid; w++) carry += ws[w];
    int exc = x - v + carry;         // exclusive prefix within bin
    int n = g * BINW + threadIdx.x;
    int n4 = l * Nc + n;
    if (n < Nc) {
        rstart[n4] = rs + exc;
        cnt[n4] = v;
        dis[n4] = rsqrtf((float)v + 1.0f);   // +1 self loop
    }
    __syncthreads();                 // all reads of hist done
    hist[threadIdx.x] = rs + exc;    // reuse as cursor
    __syncthreads();
    for (int i = rs + threadIdx.x; i < re; i += 512) {
        unsigned p = (unsigned)binned[i];
        int pos = atomicAdd(&hist[p & (BINW - 1)], 1);
        csr[pos] = (int)(p >> 9);
    }
}

// ---------------- scalar aggregation + BN stats (per layer segment) --------

__global__ void k_s_stats4(const int* __restrict__ row_start, const int* __restrict__ cnt,
                           const int* __restrict__ csr, const float* __restrict__ dis,
                           const float* __restrict__ x_nodes, float* __restrict__ s,
                           double* __restrict__ stats) {
    int l = blockIdx.x / NBK;
    int n = (blockIdx.x % NBK) * 256 + threadIdx.x;
    double v = 0.0, v2 = 0.0;
    if (n < Nc) {
        int n4 = l * Nc + n;
        const float* x = x_nodes + (size_t)l * Nc;
        const float* dl = dis + (size_t)l * Nc;
        int st = row_start[n4], en = st + cnt[n4];
        float t = 0.f;
        for (int e = st; e < en; e++) {
            int sv = csr[e];
            t += dl[sv] * x[sv];
        }
        float dn = dl[n];
        float sf = dn * t + dn * dn * x[n];   // neighbors + self loop
        s[n4] = sf;
        v = (double)sf;
        v2 = (double)sf * (double)sf;
    }
    for (int m = 32; m; m >>= 1) { v += __shfl_xor(v, m); v2 += __shfl_xor(v2, m); }
    __shared__ double r0[4], r1[4];
    int wid = threadIdx.x >> 6, lane = threadIdx.x & 63;
    if (lane == 0) { r0[wid] = v; r1[wid] = v2; }
    __syncthreads();
    if (threadIdx.x == 0) {
        atomicAdd(&stats[l * 2 + 0], r0[0] + r0[1] + r0[2] + r0[3]);
        atomicAdd(&stats[l * 2 + 1], r1[0] + r1[1] + r1[2] + r1[3]);
    }
}

__global__ void k_cvec4(const double* __restrict__ stats, const float* __restrict__ W1,
                        const float* __restrict__ gamma, float* __restrict__ cbuf) {
    int l = threadIdx.x >> 6, h = threadIdx.x & 63;  // 256 threads
    double mean = stats[l * 2] / (double)Nc;
    double var = stats[l * 2 + 1] / (double)Nc - mean * mean;
    float w = W1[l * 64 + h];
    cbuf[l * 72 + h] = gamma[l * 64 + h] * w * rsqrtf((float)var * w * w + 1e-5f);
    if (h == 0) cbuf[l * 72 + 64] = (float)mean;
}

// ---------------- per-sample node embedding (all samples, own layer) -------

__global__ __launch_bounds__(128) void k_embed4(const int* __restrict__ now,
        const int* __restrict__ lnn, const int* __restrict__ rnn,
        const int* __restrict__ row_start, const int* __restrict__ cnt,
        const int* __restrict__ csr, const float* __restrict__ dis,
        const float* __restrict__ s, const float* __restrict__ cbuf,
        const float* __restrict__ beta, const float* __restrict__ W2,
        const float* __restrict__ b2, float* __restrict__ lsb,
        unsigned short* __restrict__ lsbh) {
    int b = blockIdx.x;
    int l = now[b];
    int side = threadIdx.x >> 6, lane = threadIdx.x & 63;
    int n = side ? rnn[b] : lnn[b];
    int n4 = l * Nc + n;
    float c = cbuf[l * 72 + lane], mu = cbuf[l * 72 + 64], bt = beta[l * 64 + lane];
    const float* dl = dis + (size_t)l * Nc;
    const float* sl = s + (size_t)l * Nc;
    int st = row_start[n4], deg = cnt[n4];
    float a = 0.f;
    for (int base = 0; base < deg; base += 64) {
        int e = base + lane;
        int sv = (e < deg) ? csr[st + e] : 0;
        float nv = (e < deg) ? dl[sv] : 0.f;
        float fv = (e < deg) ? sl[sv] : 0.f;
        int m = min(64, deg - base);
        for (int j = 0; j < m; j++) {
            float nj = __shfl(nv, j);
            float fj = __shfl(fv, j);
            float hv = fmaxf(c * (fj - mu) + bt, 0.f);   // h[src][lane]
            a += nj * hv;
        }
    }
    float dn = dl[n];
    float hself = fmaxf(c * (sl[n] - mu) + bt, 0.f);
    a = dn * a + dn * dn * hself;      // acc_h[lane] for node n
    const float* W2l = W2 + (size_t)l * 64 * 128;
    const float* b2l = b2 + (size_t)l * 128;
    float o0 = b2l[lane], o1 = b2l[lane + 64];
    for (int hh = 0; hh < 64; hh++) {
        float ah = __shfl(a, hh);
        o0 += ah * W2l[hh * 128 + lane];
        o1 += ah * W2l[hh * 128 + lane + 64];
    }
    size_t obase = (size_t)b * 256 + side * 128;
    lsb[obase + lane] = o0;
    lsb[obase + lane + 64] = o1;
    lsbh[obase + lane] = f2bf(o0);
    lsbh[obase + lane + 64] = f2bf(o1);
}

// ---------------- tail kernels ----------------

// conv_w [co][ci][k] fp32 -> wbt [co][k*256+ci] bf16 (B^T layout for MFMA)
__global__ void k_wbf(const float* __restrict__ w, unsigned short* __restrict__ wbt) {
    int i = blockIdx.x * 256 + threadIdx.x; // 458752
    int co = i / KDIM;
    int r = i % KDIM;
    int ci = r / Kc, k = r % Kc;
    wbt[(size_t)co * KDIM + k * EDc + ci] = f2bf(w[i]);
}

// conv1d as bf16 MFMA GEMM: M=Bc rows(b), N=256 cols(co), K=1792.
// Block: 64 rows, 8 waves, wave = 64 rows x 32 co. A window (70 rows) staged in
// LDS (XOR-swizzled, full-column XOR); B register-double-buffered per k from
// global (L2-resident), fully unrolled so buffer selection is compile-time.
__global__ __launch_bounds__(512, 1) void k_convmma(const unsigned short* __restrict__ lsbh,
                                                    const unsigned short* __restrict__ wbt,
                                                    const float* __restrict__ cb,
                                                    float* __restrict__ sh) {
    __shared__ unsigned short lsa[70 * EDc];   // 35840 B
    int b0 = blockIdx.x * 64;
    int wid = threadIdx.x >> 6, lane = threadIdx.x & 63;
    int lrow = lane & 15, lg = lane >> 4;

    // stage A rows [b0-3, b0+67) -> LDS, byte = (r*512 + col) ^ ((r&7)<<4)
    for (int idx = threadIdx.x; idx < 70 * 32; idx += 512) {
        int r = idx >> 5, c = idx & 31;
        int grow = b0 - 3 + r;
        uint4 v = make_uint4(0u, 0u, 0u, 0u);
        if ((unsigned)grow < (unsigned)Bc)
            v = *(const uint4*)(lsbh + (size_t)grow * EDc + c * 8);
        int byte = (r * 512 + c * 16) ^ ((r & 7) << 4);
        *(uint4*)((char*)lsa + byte) = v;
    }
    __syncthreads();

    const unsigned short* w0 = wbt + (size_t)(wid * 32 + lrow) * KDIM + lg * 8;

    f32x4 acc[4][2] = {};
    bf16x8 br0[8][2], br1[8][2];

#pragma unroll
    for (int tt = 0; tt < 8; tt++)
#pragma unroll
        for (int ni = 0; ni < 2; ni++)
            br0[tt][ni] = *(const bf16x8*)(w0 + ni * 16 * KDIM + tt * 32);

#pragma unroll
    for (int k = 0; k < Kc; k++) {
        if (k < Kc - 1) {
#pragma unroll
            for (int tt = 0; tt < 8; tt++)
#pragma unroll
                for (int ni = 0; ni < 2; ni++) {
                    bf16x8 v = *(const bf16x8*)(w0 + ni * 16 * KDIM + (k + 1) * 256 + tt * 32);
                    if (k & 1) br0[tt][ni] = v; else br1[tt][ni] = v;
                }
        }
#pragma unroll
        for (int tt = 0; tt < 8; tt++) {
            bf16x8 a[4];
#pragma unroll
            for (int mi = 0; mi < 4; mi++) {
                int l = mi * 16 + lrow + k;
                a[mi] = *(const bf16x8*)((const char*)lsa + l * 512
                        + ((lg * 16 + tt * 64) ^ ((l & 7) << 4)));
            }
#pragma unroll
            for (int mi = 0; mi < 4; mi++)
#pragma unroll
                for (int ni = 0; ni < 2; ni++) {
                    bf16x8 bv = (k & 1) ? br1[tt][ni] : br0[tt][ni];
                    acc[mi][ni] = __builtin_amdgcn_mfma_f32_16x16x32_bf16(
                        a[mi], bv, acc[mi][ni], 0, 0, 0);
                }
        }
    }

#pragma unroll
    for (int mi = 0; mi < 4; mi++) {
        int rbase = b0 + mi * 16 + lg * 4;
#pragma unroll
        for (int ni = 0; ni < 2; ni++) {
            int co = wid * 32 + ni * 16 + lrow;
            float bias = cb[co];
#pragma unroll
            for (int r = 0; r < 4; r++)
                sh[(size_t)(rbase + r) * EDc + co] = fmaxf(acc[mi][ni][r] + bias, 0.0f);
        }
    }
}

__global__ void k_final(const float* __restrict__ ls, const float* __restrict__ sh,
                        const float* __restrict__ lc_w, const float* __restrict__ lc_b,
                        const float* __restrict__ link_w, const float* __restrict__ link_b,
                        float* __restrict__ out) {
    int b = blockIdx.x, lane = threadIdx.x; // 64 threads
    float lsv[4], shv[4];
    float dot = 0.f, nrm = 0.f;
#pragma unroll
    for (int i = 0; i < 4; i++) {
        int ci = lane + i * 64;
        lsv[i] = ls[b * 256 + ci];
        shv[i] = sh[b * 256 + ci];
        dot += lsv[i] * shv[i];
        nrm += shv[i] * shv[i];
    }
    for (int m = 32; m; m >>= 1) { dot += __shfl_xor(dot, m); nrm += __shfl_xor(nrm, m); }
    float coef = dot / (nrm + 1e-12f);
    float p0 = 0.f, p1 = 0.f, d0 = 0.f, d1 = 0.f, d2 = 0.f, d3 = 0.f;
#pragma unroll
    for (int i = 0; i < 4; i++) {
        int ci = lane + i * 64;
        float e = lsv[i] - coef * shv[i] + shv[i];
        p0 += e * link_w[ci * 2];
        p1 += e * link_w[ci * 2 + 1];
        d0 += shv[i] * lc_w[ci * 4];
        d1 += shv[i] * lc_w[ci * 4 + 1];
        d2 += shv[i] * lc_w[ci * 4 + 2];
        d3 += shv[i] * lc_w[ci * 4 + 3];
    }
    for (int m = 32; m; m >>= 1) {
        p0 += __shfl_xor(p0, m); p1 += __shfl_xor(p1, m);
        d0 += __shfl_xor(d0, m); d1 += __shfl_xor(d1, m);
        d2 += __shfl_xor(d2, m); d3 += __shfl_xor(d3, m);
    }
    if (lane == 0) {
        out[b * 2]     = p0 + link_b[0];
        out[b * 2 + 1] = p1 + link_b[1];
        float* dd = out + 2 * Bc;
        dd[b * 4]     = d0 + lc_b[0];
        dd[b * 4 + 1] = d1 + lc_b[1];
        dd[b * 4 + 2] = d2 + lc_b[2];
        dd[b * 4 + 3] = d3 + lc_b[3];
    }
}

// ---------------- launch ----------------

extern "C" void kernel_launch(void* const* d_in, const int* in_sizes, int n_in,
                              void* d_out, int out_size, void* d_ws, size_t ws_size,
                              hipStream_t stream) {
    const float* x_nodes    = (const float*)d_in[0];
    const int*   edge_index = (const int*)d_in[1];
    const float* W1   = (const float*)d_in[2];
    // d_in[3] = b1 (cancels in BN)
    const float* gamma = (const float*)d_in[4];
    const float* beta  = (const float*)d_in[5];
    const float* W2   = (const float*)d_in[6];
    const float* b2   = (const float*)d_in[7];
    const float* conv_w = (const float*)d_in[8];
    const float* conv_b = (const float*)d_in[9];
    const float* lc_w   = (const float*)d_in[10];
    const float* lc_b   = (const float*)d_in[11];
    const float* link_w = (const float*)d_in[12];
    const float* link_b = (const float*)d_in[13];
    const int* now = (const int*)d_in[14];
    const int* ln  = (const int*)d_in[15];
    const int* rn  = (const int*)d_in[16];
    float* out = (float*)d_out;

    char* base = (char*)d_ws;
    size_t off = 0;
    auto carve = [&](size_t bytes) {
        void* p = base + off;
        off = (off + bytes + 255) & ~(size_t)255;
        return p;
    };
    int*    binCursor = (int*)carve(NBINS * 4);
    double* stats     = (double*)carve(8 * 8);        // adjacent to binCursor: one memset
    int*    binned    = (int*)carve((size_t)NBINS * CAPc * 4);
    int*    rstart    = (int*)carve((size_t)Mtot * 4);
    int*    cnt       = (int*)carve((size_t)Mtot * 4);
    int*    csr       = (int*)carve((size_t)NBINS * CAPc * 4);
    float*  dis       = (float*)carve((size_t)Mtot * 4);
    float*  s         = (float*)carve((size_t)Mtot * 4);
    float*  cbuf      = (float*)carve(Lc * 72 * 4);
    float*  lsb       = (float*)carve((size_t)Bc * 256 * 4);
    float*  shb       = (float*)carve((size_t)Bc * 256 * 4);
    unsigned short* lsbh = (unsigned short*)carve((size_t)Bc * 256 * 2);
    unsigned short* wbt  = (unsigned short*)carve((size_t)EDc * KDIM * 2);
    (void)ws_size;

    const int FBLK = (Ec + CHUNK - 1) / CHUNK;   // 98

    hipMemsetAsync(binCursor, 0, (char*)(stats + 8) - (char*)binCursor, stream);
    k_wbf<<<1792, 256, 0, stream>>>(conv_w, wbt);

    k_binfill<<<dim3(FBLK, Lc), 256, 0, stream>>>(edge_index, binCursor, binned);
    k_csr<<<NBINS, 512, 0, stream>>>(binCursor, binned, csr, rstart, cnt, dis);
    k_s_stats4<<<NBK * Lc, 256, 0, stream>>>(rstart, cnt, csr, dis, x_nodes, s, stats);
    k_cvec4<<<1, 256, 0, stream>>>(stats, W1, gamma, cbuf);
    k_embed4<<<Bc, 128, 0, stream>>>(now, ln, rn, rstart, cnt, csr, dis, s,
                                     cbuf, beta, W2, b2, lsb, lsbh);

    k_convmma<<<Bc / 64, 512, 0, stream>>>(lsbh, wbt, conv_b, shb);
    k_final<<<Bc, 64, 0, stream>>>(lsb, shb, lc_w, lc_b, link_w, link_b, out);
}

// Round 9
// 185.343 us; speedup vs baseline: 9.6410x; 1.1334x over previous
//
#include <hip/hip_runtime.h>
#include <hip/hip_bf16.h>

#define Lc 4
#define Nc 50000
#define Ec 800000
#define Bc 16384
#define EDc 256
#define Kc 7
#define Mtot (Lc * Nc)      // 200000 nodes total
#define KDIM (EDc * Kc)     // 1792

#define BINW 512            // nodes per bin
#define FB 98               // bins per layer = ceil(50000/512)
#define NBINS (FB * Lc)     // 392
#define CAPc 12288          // fixed bin capacity (mean 8192, sigma ~90)
#define CHUNK 8192          // edges per binfill block

typedef __attribute__((ext_vector_type(8))) short bf16x8;
typedef __attribute__((ext_vector_type(4))) float f32x4;

static __device__ __forceinline__ unsigned short f2bf(float f) {
    unsigned u = __float_as_uint(f);
    unsigned r = (u + 0x7fffu + ((u >> 16) & 1u)) >> 16;
    return (unsigned short)r;
}

// ---------------- binned edge sort (fixed-capacity bins, no scan) ----------

__global__ void k_binfill(const int* __restrict__ ei, int* __restrict__ binCursor,
                          int* __restrict__ binned) {
    int l = blockIdx.y;
    int e0 = blockIdx.x * CHUNK;
    __shared__ int lh[FB], lcur[FB];
    if (threadIdx.x < FB) lh[threadIdx.x] = 0;
    __syncthreads();
    const int* srcp = ei + (size_t)l * 2 * Ec;
    const int* dstp = srcp + Ec;
#pragma unroll
    for (int it = 0; it < CHUNK / 256; it++) {
        int idx = e0 + it * 256 + threadIdx.x;
        if (idx < Ec) atomicAdd(&lh[dstp[idx] >> 9], 1);
    }
    __syncthreads();
    if (threadIdx.x < FB) {
        int c = lh[threadIdx.x];
        int bin = l * FB + threadIdx.x;
        int st = c ? atomicAdd(&binCursor[bin], c) : 0;
        lcur[threadIdx.x] = bin * CAPc + min(st, CAPc);
        lh[threadIdx.x] = bin * CAPc + CAPc;    // reuse as limit
    }
    __syncthreads();
#pragma unroll
    for (int it = 0; it < CHUNK / 256; it++) {
        int idx = e0 + it * 256 + threadIdx.x;
        if (idx < Ec) {
            int d = dstp[idx], sv = srcp[idx];
            int t = d >> 9;
            int pos = atomicAdd(&lcur[t], 1);
            if (pos < lh[t]) binned[pos] = (sv << 9) | (d & (BINW - 1));
        }
    }
}

// one block per bin: build final CSR segment + per-node cnt/rstart/dis/g
__global__ __launch_bounds__(512) void k_csr(const int* __restrict__ binCnt,
                                             const int* __restrict__ binned,
                                             const float* __restrict__ x_nodes,
                                             int* __restrict__ csr,
                                             int* __restrict__ rstart,
                                             int* __restrict__ cnt,
                                             float* __restrict__ dis,
                                             float* __restrict__ g) {
    int b = blockIdx.x;              // 0..NBINS-1
    int l = b / FB, gg = b % FB;
    int rs = b * CAPc;
    int cntb = binCnt[b];
    if (cntb > CAPc) cntb = CAPc;
    int re = rs + cntb;
    __shared__ int hist[BINW];
    hist[threadIdx.x] = 0;
    __syncthreads();
    for (int i = rs + threadIdx.x; i < re; i += 512)
        atomicAdd(&hist[binned[i] & (BINW - 1)], 1);
    __syncthreads();
    int lane = threadIdx.x & 63, wid = threadIdx.x >> 6;
    int v = hist[threadIdx.x];
    int x = v;
#pragma unroll
    for (int off = 1; off < 64; off <<= 1) {
        int y = __shfl_up(x, off);
        if (lane >= off) x += y;
    }
    __shared__ int ws[8];
    if (lane == 63) ws[wid] = x;
    __syncthreads();
    int carry = 0;
    for (int w = 0; w < wid; w++) carry += ws[w];
    int exc = x - v + carry;         // exclusive prefix within bin
    int n = gg * BINW + threadIdx.x;
    int n4 = l * Nc + n;
    if (n < Nc) {
        rstart[n4] = rs + exc;
        cnt[n4] = v;
        float dn = rsqrtf((float)v + 1.0f);   // +1 self loop
        dis[n4] = dn;
        g[n4] = dn * x_nodes[(size_t)l * Nc + n];
    }
    __syncthreads();                 // all reads of hist done
    hist[threadIdx.x] = rs + exc;    // reuse as cursor
    __syncthreads();
    for (int i = rs + threadIdx.x; i < re; i += 512) {
        unsigned p = (unsigned)binned[i];
        int pos = atomicAdd(&hist[p & (BINW - 1)], 1);
        csr[pos] = (int)(p >> 9);
    }
}

// ---------------- edge-parallel s aggregation + BN stats (per bin) ---------

__global__ __launch_bounds__(512) void k_s_bin(const int* __restrict__ binCnt,
                                               const int* __restrict__ binned,
                                               const float* __restrict__ g,
                                               const float* __restrict__ dis,
                                               float* __restrict__ s,
                                               double* __restrict__ stats) {
    int b = blockIdx.x;              // 0..NBINS-1
    int l = b / FB, gg = b % FB;
    int rs = b * CAPc;
    int cntb = binCnt[b];
    if (cntb > CAPc) cntb = CAPc;
    int re = rs + cntb;
    const float* gl = g + (size_t)l * Nc;
    __shared__ float acc[BINW];
    acc[threadIdx.x] = 0.f;
    __syncthreads();
    for (int i = rs + threadIdx.x; i < re; i += 512) {
        unsigned p = (unsigned)binned[i];
        atomicAdd(&acc[p & (BINW - 1)], gl[p >> 9]);   // LDS fp32 atomic
    }
    __syncthreads();
    int n = gg * BINW + threadIdx.x;
    int n4 = l * Nc + n;
    double v = 0.0, v2 = 0.0;
    if (n < Nc) {
        float dn = dis[n4];
        float sf = dn * (acc[threadIdx.x] + g[n4]);  // neighbors + self loop
        s[n4] = sf;
        v = (double)sf;
        v2 = (double)sf * (double)sf;
    }
    for (int m = 32; m; m >>= 1) { v += __shfl_xor(v, m); v2 += __shfl_xor(v2, m); }
    __shared__ double r0[8], r1[8];
    int wid = threadIdx.x >> 6, lane = threadIdx.x & 63;
    if (lane == 0) { r0[wid] = v; r1[wid] = v2; }
    __syncthreads();
    if (threadIdx.x == 0) {
        double a = 0, bb = 0;
        for (int w = 0; w < 8; w++) { a += r0[w]; bb += r1[w]; }
        atomicAdd(&stats[l * 2 + 0], a);
        atomicAdd(&stats[l * 2 + 1], bb);
    }
}

__global__ void k_cvec4(const double* __restrict__ stats, const float* __restrict__ W1,
                        const float* __restrict__ gamma, float* __restrict__ cbuf) {
    int l = threadIdx.x >> 6, h = threadIdx.x & 63;  // 256 threads
    double mean = stats[l * 2] / (double)Nc;
    double var = stats[l * 2 + 1] / (double)Nc - mean * mean;
    float w = W1[l * 64 + h];
    cbuf[l * 72 + h] = gamma[l * 64 + h] * w * rsqrtf((float)var * w * w + 1e-5f);
    if (h == 0) cbuf[l * 72 + 64] = (float)mean;
}

// ---------------- per-sample node embedding (all samples, own layer) -------

__global__ __launch_bounds__(128) void k_embed4(const int* __restrict__ now,
        const int* __restrict__ lnn, const int* __restrict__ rnn,
        const int* __restrict__ row_start, const int* __restrict__ cnt,
        const int* __restrict__ csr, const float* __restrict__ dis,
        const float* __restrict__ s, const float* __restrict__ cbuf,
        const float* __restrict__ beta, const float* __restrict__ W2,
        const float* __restrict__ b2, float* __restrict__ lsb,
        unsigned short* __restrict__ lsbh) {
    int b = blockIdx.x;
    int l = now[b];
    int side = threadIdx.x >> 6, lane = threadIdx.x & 63;
    int n = side ? rnn[b] : lnn[b];
    int n4 = l * Nc + n;
    float c = cbuf[l * 72 + lane], mu = cbuf[l * 72 + 64], bt = beta[l * 64 + lane];
    const float* dl = dis + (size_t)l * Nc;
    const float* sl = s + (size_t)l * Nc;
    int st = row_start[n4], deg = cnt[n4];
    float a = 0.f;
    for (int base = 0; base < deg; base += 64) {
        int e = base + lane;
        int sv = (e < deg) ? csr[st + e] : 0;
        float nv = (e < deg) ? dl[sv] : 0.f;
        float fv = (e < deg) ? sl[sv] : 0.f;
        int m = min(64, deg - base);
        for (int j = 0; j < m; j++) {
            float nj = __shfl(nv, j);
            float fj = __shfl(fv, j);
            float hv = fmaxf(c * (fj - mu) + bt, 0.f);   // h[src][lane]
            a += nj * hv;
        }
    }
    float dn = dl[n];
    float hself = fmaxf(c * (sl[n] - mu) + bt, 0.f);
    a = dn * a + dn * dn * hself;      // acc_h[lane] for node n
    const float* W2l = W2 + (size_t)l * 64 * 128;
    const float* b2l = b2 + (size_t)l * 128;
    float o0 = b2l[lane], o1 = b2l[lane + 64];
    for (int hh = 0; hh < 64; hh++) {
        float ah = __shfl(a, hh);
        o0 += ah * W2l[hh * 128 + lane];
        o1 += ah * W2l[hh * 128 + lane + 64];
    }
    size_t obase = (size_t)b * 256 + side * 128;
    lsb[obase + lane] = o0;
    lsb[obase + lane + 64] = o1;
    lsbh[obase + lane] = f2bf(o0);
    lsbh[obase + lane + 64] = f2bf(o1);
}

// ---------------- tail kernels ----------------

// conv_w [co][ci][k] fp32 -> wbt [co][k*256+ci] bf16 (B^T layout for MFMA)
__global__ void k_wbf(const float* __restrict__ w, unsigned short* __restrict__ wbt) {
    int i = blockIdx.x * 256 + threadIdx.x; // 458752
    int co = i / KDIM;
    int r = i % KDIM;
    int ci = r / Kc, k = r % Kc;
    wbt[(size_t)co * KDIM + k * EDc + ci] = f2bf(w[i]);
}

// conv1d as bf16 MFMA GEMM: M=Bc rows(b), N=256 cols(co), K=1792.
// Block: 64 rows, 8 waves, wave = 64 rows x 32 co. A window (70 rows) staged in
// LDS (XOR-swizzled, full-column XOR); B register-double-buffered per k from
// global (L2-resident), fully unrolled so buffer selection is compile-time.
__global__ __launch_bounds__(512, 1) void k_convmma(const unsigned short* __restrict__ lsbh,
                                                    const unsigned short* __restrict__ wbt,
                                                    const float* __restrict__ cb,
                                                    float* __restrict__ sh) {
    __shared__ unsigned short lsa[70 * EDc];   // 35840 B
    int b0 = blockIdx.x * 64;
    int wid = threadIdx.x >> 6, lane = threadIdx.x & 63;
    int lrow = lane & 15, lg = lane >> 4;

    // stage A rows [b0-3, b0+67) -> LDS, byte = (r*512 + col) ^ ((r&7)<<4)
    for (int idx = threadIdx.x; idx < 70 * 32; idx += 512) {
        int r = idx >> 5, c = idx & 31;
        int grow = b0 - 3 + r;
        uint4 v = make_uint4(0u, 0u, 0u, 0u);
        if ((unsigned)grow < (unsigned)Bc)
            v = *(const uint4*)(lsbh + (size_t)grow * EDc + c * 8);
        int byte = (r * 512 + c * 16) ^ ((r & 7) << 4);
        *(uint4*)((char*)lsa + byte) = v;
    }
    __syncthreads();

    const unsigned short* w0 = wbt + (size_t)(wid * 32 + lrow) * KDIM + lg * 8;

    f32x4 acc[4][2] = {};
    bf16x8 br0[8][2], br1[8][2];

#pragma unroll
    for (int tt = 0; tt < 8; tt++)
#pragma unroll
        for (int ni = 0; ni < 2; ni++)
            br0[tt][ni] = *(const bf16x8*)(w0 + ni * 16 * KDIM + tt * 32);

#pragma unroll
    for (int k = 0; k < Kc; k++) {
        if (k < Kc - 1) {
#pragma unroll
            for (int tt = 0; tt < 8; tt++)
#pragma unroll
                for (int ni = 0; ni < 2; ni++) {
                    bf16x8 v = *(const bf16x8*)(w0 + ni * 16 * KDIM + (k + 1) * 256 + tt * 32);
                    if (k & 1) br0[tt][ni] = v; else br1[tt][ni] = v;
                }
        }
#pragma unroll
        for (int tt = 0; tt < 8; tt++) {
            bf16x8 a[4];
#pragma unroll
            for (int mi = 0; mi < 4; mi++) {
                int l = mi * 16 + lrow + k;
                a[mi] = *(const bf16x8*)((const char*)lsa + l * 512
                        + ((lg * 16 + tt * 64) ^ ((l & 7) << 4)));
            }
#pragma unroll
            for (int mi = 0; mi < 4; mi++)
#pragma unroll
                for (int ni = 0; ni < 2; ni++) {
                    bf16x8 bv = (k & 1) ? br1[tt][ni] : br0[tt][ni];
                    acc[mi][ni] = __builtin_amdgcn_mfma_f32_16x16x32_bf16(
                        a[mi], bv, acc[mi][ni], 0, 0, 0);
                }
        }
    }

#pragma unroll
    for (int mi = 0; mi < 4; mi++) {
        int rbase = b0 + mi * 16 + lg * 4;
#pragma unroll
        for (int ni = 0; ni < 2; ni++) {
            int co = wid * 32 + ni * 16 + lrow;
            float bias = cb[co];
#pragma unroll
            for (int r = 0; r < 4; r++)
                sh[(size_t)(rbase + r) * EDc + co] = fmaxf(acc[mi][ni][r] + bias, 0.0f);
        }
    }
}

__global__ void k_final(const float* __restrict__ ls, const float* __restrict__ sh,
                        const float* __restrict__ lc_w, const float* __restrict__ lc_b,
                        const float* __restrict__ link_w, const float* __restrict__ link_b,
                        float* __restrict__ out) {
    int b = blockIdx.x, lane = threadIdx.x; // 64 threads
    float lsv[4], shv[4];
    float dot = 0.f, nrm = 0.f;
#pragma unroll
    for (int i = 0; i < 4; i++) {
        int ci = lane + i * 64;
        lsv[i] = ls[b * 256 + ci];
        shv[i] = sh[b * 256 + ci];
        dot += lsv[i] * shv[i];
        nrm += shv[i] * shv[i];
    }
    for (int m = 32; m; m >>= 1) { dot += __shfl_xor(dot, m); nrm += __shfl_xor(nrm, m); }
    float coef = dot / (nrm + 1e-12f);
    float p0 = 0.f, p1 = 0.f, d0 = 0.f, d1 = 0.f, d2 = 0.f, d3 = 0.f;
#pragma unroll
    for (int i = 0; i < 4; i++) {
        int ci = lane + i * 64;
        float e = lsv[i] - coef * shv[i] + shv[i];
        p0 += e * link_w[ci * 2];
        p1 += e * link_w[ci * 2 + 1];
        d0 += shv[i] * lc_w[ci * 4];
        d1 += shv[i] * lc_w[ci * 4 + 1];
        d2 += shv[i] * lc_w[ci * 4 + 2];
        d3 += shv[i] * lc_w[ci * 4 + 3];
    }
    for (int m = 32; m; m >>= 1) {
        p0 += __shfl_xor(p0, m); p1 += __shfl_xor(p1, m);
        d0 += __shfl_xor(d0, m); d1 += __shfl_xor(d1, m);
        d2 += __shfl_xor(d2, m); d3 += __shfl_xor(d3, m);
    }
    if (lane == 0) {
        out[b * 2]     = p0 + link_b[0];
        out[b * 2 + 1] = p1 + link_b[1];
        float* dd = out + 2 * Bc;
        dd[b * 4]     = d0 + lc_b[0];
        dd[b * 4 + 1] = d1 + lc_b[1];
        dd[b * 4 + 2] = d2 + lc_b[2];
        dd[b * 4 + 3] = d3 + lc_b[3];
    }
}

// ---------------- launch ----------------

extern "C" void kernel_launch(void* const* d_in, const int* in_sizes, int n_in,
                              void* d_out, int out_size, void* d_ws, size_t ws_size,
                              hipStream_t stream) {
    const float* x_nodes    = (const float*)d_in[0];
    const int*   edge_index = (const int*)d_in[1];
    const float* W1   = (const float*)d_in[2];
    // d_in[3] = b1 (cancels in BN)
    const float* gamma = (const float*)d_in[4];
    const float* beta  = (const float*)d_in[5];
    const float* W2   = (const float*)d_in[6];
    const float* b2   = (const float*)d_in[7];
    const float* conv_w = (const float*)d_in[8];
    const float* conv_b = (const float*)d_in[9];
    const float* lc_w   = (const float*)d_in[10];
    const float* lc_b   = (const float*)d_in[11];
    const float* link_w = (const float*)d_in[12];
    const float* link_b = (const float*)d_in[13];
    const int* now = (const int*)d_in[14];
    const int* ln  = (const int*)d_in[15];
    const int* rn  = (const int*)d_in[16];
    float* out = (float*)d_out;

    char* base = (char*)d_ws;
    size_t off = 0;
    auto carve = [&](size_t bytes) {
        void* p = base + off;
        off = (off + bytes + 255) & ~(size_t)255;
        return p;
    };
    int*    binCursor = (int*)carve(NBINS * 4);
    double* stats     = (double*)carve(8 * 8);        // adjacent to binCursor: one memset
    int*    binned    = (int*)carve((size_t)NBINS * CAPc * 4);
    int*    rstart    = (int*)carve((size_t)Mtot * 4);
    int*    cnt       = (int*)carve((size_t)Mtot * 4);
    int*    csr       = (int*)carve((size_t)NBINS * CAPc * 4);
    float*  dis       = (float*)carve((size_t)Mtot * 4);
    float*  s         = (float*)carve((size_t)Mtot * 4);
    float*  g         = (float*)carve((size_t)Mtot * 4);
    float*  cbuf      = (float*)carve(Lc * 72 * 4);
    float*  lsb       = (float*)carve((size_t)Bc * 256 * 4);
    float*  shb       = (float*)carve((size_t)Bc * 256 * 4);
    unsigned short* lsbh = (unsigned short*)carve((size_t)Bc * 256 * 2);
    unsigned short* wbt  = (unsigned short*)carve((size_t)EDc * KDIM * 2);
    (void)ws_size;

    const int FBLK = (Ec + CHUNK - 1) / CHUNK;   // 98

    hipMemsetAsync(binCursor, 0, (char*)(stats + 8) - (char*)binCursor, stream);
    k_wbf<<<1792, 256, 0, stream>>>(conv_w, wbt);

    k_binfill<<<dim3(FBLK, Lc), 256, 0, stream>>>(edge_index, binCursor, binned);
    k_csr<<<NBINS, 512, 0, stream>>>(binCursor, binned, x_nodes, csr, rstart, cnt, dis, g);
    k_s_bin<<<NBINS, 512, 0, stream>>>(binCursor, binned, g, dis, s, stats);
    k_cvec4<<<1, 256, 0, stream>>>(stats, W1, gamma, cbuf);
    k_embed4<<<Bc, 128, 0, stream>>>(now, ln, rn, rstart, cnt, csr, dis, s,
                                     cbuf, beta, W2, b2, lsb, lsbh);

    k_convmma<<<Bc / 64, 512, 0, stream>>>(lsbh, wbt, conv_b, shb);
    k_final<<<Bc, 64, 0, stream>>>(lsb, shb, lc_w, lc_b, link_w, link_b, out);
}